// Round 2
// baseline (6108.657 us; speedup 1.0000x reference)
//
#include <hip/hip_runtime.h>
#include <hip/hip_bf16.h>
#include <cstdint>

// mamba_model: DEPTH=2, B=4, L=4096, DM=512, DI=1024, DS=16, DTR=32, K=4
// Round 2: same fp32 pipeline as R1, but the workspace is sized adaptively.
// R1 died with an HSA memory-fault abort; the only unverified assumption was
// ws_size >= 292 MiB. All intermediates factor per-batch (conv is causal
// within a batch, scan is per-batch), so we process batches in chunks of
// CB in {4,2,1} picked from ws_size (constant per session -> same work every
// call). Per-batch chunk footprint: 4096*(512+2048+1024+64+1024) floats
// = 73 MiB.  Gated y is written into the dead xq half of xz (stride 2*DI).

#define BATCH 4
#define SEQL  4096
#define DMv   512
#define DIv   1024
#define DSv   16
#define DTRv  32
#define KCv   4

// ---------------- LayerNorm: one 64-thread wave per row of 512 ----------------
__global__ __launch_bounds__(64) void ln_kernel(
    const float* __restrict__ in, const float* __restrict__ w,
    const float* __restrict__ b, float* __restrict__ out)
{
    const int row = blockIdx.x;
    const int t = threadIdx.x;
    const float* xr = in + (size_t)row * DMv;
    float4 v0 = *(const float4*)(xr + t * 4);
    float4 v1 = *(const float4*)(xr + 256 + t * 4);
    float s = v0.x + v0.y + v0.z + v0.w + v1.x + v1.y + v1.z + v1.w;
    float q = v0.x*v0.x + v0.y*v0.y + v0.z*v0.z + v0.w*v0.w
            + v1.x*v1.x + v1.y*v1.y + v1.z*v1.z + v1.w*v1.w;
    s += __shfl_xor(s, 1);  q += __shfl_xor(q, 1);
    s += __shfl_xor(s, 2);  q += __shfl_xor(q, 2);
    s += __shfl_xor(s, 4);  q += __shfl_xor(q, 4);
    s += __shfl_xor(s, 8);  q += __shfl_xor(q, 8);
    s += __shfl_xor(s, 16); q += __shfl_xor(q, 16);
    s += __shfl_xor(s, 32); q += __shfl_xor(q, 32);
    const float mean = s * (1.0f / DMv);
    const float var  = q * (1.0f / DMv) - mean * mean;
    const float rs   = rsqrtf(var + 1e-5f);

    float4 w0 = *(const float4*)(w + t * 4);
    float4 w1 = *(const float4*)(w + 256 + t * 4);
    float4 b0 = *(const float4*)(b + t * 4);
    float4 b1 = *(const float4*)(b + 256 + t * 4);
    float4 o0, o1;
    o0.x = (v0.x - mean) * rs * w0.x + b0.x;
    o0.y = (v0.y - mean) * rs * w0.y + b0.y;
    o0.z = (v0.z - mean) * rs * w0.z + b0.z;
    o0.w = (v0.w - mean) * rs * w0.w + b0.w;
    o1.x = (v1.x - mean) * rs * w1.x + b1.x;
    o1.y = (v1.y - mean) * rs * w1.y + b1.y;
    o1.z = (v1.z - mean) * rs * w1.z + b1.z;
    o1.w = (v1.w - mean) * rs * w1.w + b1.w;
    float* orow = out + (size_t)row * DMv;
    *(float4*)(orow + t * 4)       = o0;
    *(float4*)(orow + 256 + t * 4) = o1;
}

// ---------------- fp32 GEMM, C[M,N] = A[M,K] * W[N,K]^T  (both K-contiguous) --
// 64x64 tile, BK=16, 256 threads, 4x4 microtile.
__global__ __launch_bounds__(256) void sgemm_bt(
    const float* __restrict__ A, int lda,
    const float* __restrict__ W, int ldw,
    float* __restrict__ C, int ldc, int Kdim)
{
    __shared__ float As[16][68];
    __shared__ float Ws[16][68];
    const int t  = threadIdx.x;
    const int m0 = blockIdx.y * 64;
    const int n0 = blockIdx.x * 64;
    const int rr = t >> 2;           // 0..63 staging row
    const int kq = (t & 3) << 2;     // 0,4,8,12 staging k
    const float* Ap = A + (size_t)(m0 + rr) * lda + kq;
    const float* Wp = W + (size_t)(n0 + rr) * ldw + kq;
    const int tm = (t >> 4) << 2;    // microtile m offset 0..60
    const int tn = (t & 15) << 2;    // microtile n offset 0..60

    float acc[4][4];
#pragma unroll
    for (int i = 0; i < 4; i++)
#pragma unroll
        for (int j = 0; j < 4; j++) acc[i][j] = 0.0f;

    for (int k0 = 0; k0 < Kdim; k0 += 16) {
        __syncthreads();
        float4 av = *(const float4*)(Ap + k0);
        float4 wv = *(const float4*)(Wp + k0);
        As[kq + 0][rr] = av.x; As[kq + 1][rr] = av.y;
        As[kq + 2][rr] = av.z; As[kq + 3][rr] = av.w;
        Ws[kq + 0][rr] = wv.x; Ws[kq + 1][rr] = wv.y;
        Ws[kq + 2][rr] = wv.z; Ws[kq + 3][rr] = wv.w;
        __syncthreads();
#pragma unroll
        for (int k = 0; k < 16; k++) {
            float4 a4 = *(const float4*)&As[k][tm];
            float4 b4 = *(const float4*)&Ws[k][tn];
            float a[4] = {a4.x, a4.y, a4.z, a4.w};
            float bb[4] = {b4.x, b4.y, b4.z, b4.w};
#pragma unroll
            for (int i = 0; i < 4; i++)
#pragma unroll
                for (int j = 0; j < 4; j++) acc[i][j] += a[i] * bb[j];
        }
    }
    const int mb = m0 + tm;
    const int nb = n0 + tn;
#pragma unroll
    for (int i = 0; i < 4; i++) {
        float4 o = make_float4(acc[i][0], acc[i][1], acc[i][2], acc[i][3]);
        *(float4*)(C + (size_t)(mb + i) * ldc + nb) = o;
    }
}

// ---------------- depthwise causal conv(K=4) + bias + silu --------------------
// one block per (chunk-relative) row; threads cover DI channels in 4 chunks.
__global__ __launch_bounds__(256) void conv_silu_kernel(
    const float* __restrict__ xz, const float* __restrict__ cw,
    const float* __restrict__ cb, float* __restrict__ xc)
{
    const int bl = blockIdx.x;          // chunk-relative row (whole batches)
    const int l  = bl & (SEQL - 1);
    const int t  = threadIdx.x;
#pragma unroll
    for (int j = 0; j < 4; j++) {
        const int c = (j << 8) + t;
        float4 w4 = *(const float4*)(cw + c * 4);
        float wk[4] = {w4.x, w4.y, w4.z, w4.w};
        float acc = cb[c];
#pragma unroll
        for (int k = 0; k < KCv; k++) {
            const int lp = l - 3 + k;
            if (lp >= 0) {
                const long rowi = (long)bl + k - 3;   // same batch, earlier l
                acc += xz[(size_t)rowi * (2 * DIv) + c] * wk[k];
            }
        }
        const float sg = acc / (1.0f + __expf(-acc));
        xc[(size_t)bl * DIv + c] = sg;
    }
}

// ---------------- dt = softplus(dtr @ dt_w^T + dt_b) --------------------------
__global__ __launch_bounds__(256) void dtk_kernel(
    const float* __restrict__ dbl, const float* __restrict__ dt_w,
    const float* __restrict__ dt_b, float* __restrict__ dt)
{
    __shared__ float s_dtr[128][32];
    const int t  = threadIdx.x;
    const int r0 = blockIdx.x * 128;
    const int di = blockIdx.y * 256 + t;

    float w[32];
    const float4* wp = (const float4*)(dt_w + (size_t)di * DTRv);
#pragma unroll
    for (int j = 0; j < 8; j++) {
        float4 v = wp[j];
        w[j * 4 + 0] = v.x; w[j * 4 + 1] = v.y; w[j * 4 + 2] = v.z; w[j * 4 + 3] = v.w;
    }
    const float bias = dt_b[di];

    for (int e = t; e < 128 * 32; e += 256) {
        const int r = e >> 5, k = e & 31;
        s_dtr[r][k] = dbl[(size_t)(r0 + r) * 64 + k];
    }
    __syncthreads();

    for (int r = 0; r < 128; r++) {
        float acc = bias;
#pragma unroll
        for (int k = 0; k < 32; k++) acc += s_dtr[r][k] * w[k];
        const float sp = (acc > 20.0f) ? acc : log1pf(__expf(acc));
        dt[(size_t)(r0 + r) * DIv + di] = sp;
    }
}

// ---------------- selective scan + gate ---------------------------------------
// One lane per (b, di, ds) state. Block = 256 threads = 16 di x 16 ds.
// 8-deep prefetch ring hides L2/L3 latency in the serial l-loop.
// Reads z from xz[...,DI:], writes gated y into xz[...,:DI] (xq half is dead).
#define PF 8
__global__ __launch_bounds__(256) void scan_kernel(
    const float* __restrict__ dt, const float* __restrict__ xc,
    const float* __restrict__ dbl, const float* __restrict__ A_log,
    const float* __restrict__ Dp, float* xzbuf)
{
    const int b   = blockIdx.x >> 6;           // batch index within chunk
    const int di0 = (blockIdx.x & 63) << 4;
    const int t   = threadIdx.x;
    const int ds  = t & 15;
    const int dil = t >> 4;
    const int di  = di0 + dil;

    const float Areg = -__expf(A_log[di * DSv + ds]);
    const float Dv   = Dp[di];

    const float* dtp = dt + (size_t)b * SEQL * DIv + di;
    const float* xp  = xc + (size_t)b * SEQL * DIv + di;
    const float* blp = dbl + (size_t)b * SEQL * 64;
    float* zgp = xzbuf + (size_t)b * SEQL * (2 * DIv);

    float rdt[PF], rx[PF], rB[PF], rC[PF], rz[PF];
#pragma unroll
    for (int i = 0; i < PF; i++) {
        rdt[i] = dtp[(size_t)i * DIv];
        rx[i]  = xp[(size_t)i * DIv];
        rB[i]  = blp[i * 64 + 32 + ds];
        rC[i]  = blp[i * 64 + 48 + ds];
        rz[i]  = zgp[(size_t)i * (2 * DIv) + DIv + di];
    }

    float h = 0.0f;
    for (int l0 = 0; l0 < SEQL; l0 += PF) {
#pragma unroll
        for (int j = 0; j < PF; j++) {
            const int l = l0 + j;
            const float dtv = rdt[j], xv = rx[j], Bv = rB[j], Cv = rC[j], zv = rz[j];
            const int lp  = l + PF;
            const int lpc = (lp < SEQL) ? lp : (SEQL - 1);
            rdt[j] = dtp[(size_t)lpc * DIv];
            rx[j]  = xp[(size_t)lpc * DIv];
            rB[j]  = blp[lpc * 64 + 32 + ds];
            rC[j]  = blp[lpc * 64 + 48 + ds];
            rz[j]  = zgp[(size_t)lpc * (2 * DIv) + DIv + di];

            const float dA = __expf(dtv * Areg);
            h = h * dA + (dtv * xv) * Bv;
            float p = h * Cv;
            p += __shfl_xor(p, 1);
            p += __shfl_xor(p, 2);
            p += __shfl_xor(p, 4);
            p += __shfl_xor(p, 8);
            if (ds == 0) {
                const float y  = p + xv * Dv;
                const float sg = zv / (1.0f + __expf(-zv));
                zgp[(size_t)l * (2 * DIv) + di] = y * sg;
            }
        }
    }
}

extern "C" void kernel_launch(void* const* d_in, const int* in_sizes, int n_in,
                              void* d_out, int out_size, void* d_ws, size_t ws_size,
                              hipStream_t stream)
{
    const float* x       = (const float*)d_in[0];
    const float* ln_w    = (const float*)d_in[1];
    const float* ln_b    = (const float*)d_in[2];
    const float* in_w    = (const float*)d_in[3];
    const float* conv_w  = (const float*)d_in[4];
    const float* conv_b  = (const float*)d_in[5];
    const float* xproj_w = (const float*)d_in[6];
    const float* dt_w    = (const float*)d_in[7];
    const float* dt_b    = (const float*)d_in[8];
    const float* A_log   = (const float*)d_in[9];
    const float* Dvec    = (const float*)d_in[10];
    const float* out_w   = (const float*)d_in[11];
    float* out = (float*)d_out;

    // Bytes of scratch needed per batch of the chunk:
    //   hn DM + xz 2*DI + xc DI + dbl 64 + dt DI  per row, 4096 rows.
    const size_t perb = (size_t)SEQL * (DMv + 2 * DIv + DIv + 64 + DIv) * sizeof(float);
    // CB is a pure function of ws_size -> identical work on every call.
    const int CB = (ws_size >= 4 * perb) ? 4 : (ws_size >= 2 * perb) ? 2 : 1;

    for (int i = 0; i < 2; i++) {
        const float* hin_base = (i == 0) ? x : out;   // layer output lives in d_out
        for (int c0 = 0; c0 < BATCH; c0 += CB) {
            const int MR = CB * SEQL;                 // rows in this chunk
            float* ws  = (float*)d_ws;
            float* hn  = ws;                          // MR*DM
            float* xz  = hn  + (size_t)MR * DMv;      // MR*2*DI
            float* xc  = xz  + (size_t)MR * 2 * DIv;  // MR*DI
            float* dbl = xc  + (size_t)MR * DIv;      // MR*64
            float* dtb = dbl + (size_t)MR * 64;       // MR*DI
            const size_t row0 = (size_t)c0 * SEQL;

            ln_kernel<<<MR, 64, 0, stream>>>(
                hin_base + row0 * DMv, ln_w + i * DMv, ln_b + i * DMv, hn);
            // in-proj: (MRx512) * (2048x512)^T -> xz (MRx2048)
            sgemm_bt<<<dim3(2 * DIv / 64, MR / 64), 256, 0, stream>>>(
                hn, DMv, in_w + (size_t)i * 2 * DIv * DMv, DMv, xz, 2 * DIv, DMv);
            conv_silu_kernel<<<MR, 256, 0, stream>>>(
                xz, conv_w + i * DIv * KCv, conv_b + i * DIv, xc);
            // x-proj: (MRx1024) * (64x1024)^T -> dbl (MRx64)
            sgemm_bt<<<dim3(1, MR / 64), 256, 0, stream>>>(
                xc, DIv, xproj_w + (size_t)i * 64 * DIv, DIv, dbl, 64, DIv);
            dtk_kernel<<<dim3(MR / 128, DIv / 256), 256, 0, stream>>>(
                dbl, dt_w + (size_t)i * DIv * DTRv, dt_b + i * DIv, dtb);
            scan_kernel<<<CB * (DIv / 16), 256, 0, stream>>>(
                dtb, xc, dbl, A_log + (size_t)i * DIv * DSv, Dvec + i * DIv, xz);
            // out-proj: gated y (lda=2*DI, aliased in xz) * (512x1024)^T -> out
            sgemm_bt<<<dim3(DMv / 64, MR / 64), 256, 0, stream>>>(
                xz, 2 * DIv, out_w + (size_t)i * DMv * DIv, DIv, out + row0 * DMv, DMv, DIv);
        }
    }
}

// Round 3
// 2493.586 us; speedup vs baseline: 2.4497x; 2.4497x over previous
//
#include <hip/hip_runtime.h>
#include <hip/hip_bf16.h>
#include <cstdint>

// mamba_model: DEPTH=2, B=4, L=4096, DM=512, DI=1024, DS=16, DTR=32, K=4
// Round 3: replace the serial scan (4x1037us, 6% occupancy, latency-bound)
// with a 3-phase chunked linear-recurrence scan over L (NG=64 chunks of LC=64):
//   p1: per (b,di,chunk): local decay product P[ds] & zero-seeded state S[ds]
//   p2: per (b,di,ds): sequential combine over 64 chunks; Sbuf <- chunk seeds
//   p3: per (b,di,chunk): re-run local recurrence from seed, y = sum_ds h*C
//       (+ x*D), gate with silu(z), write into dead xq half of xz.
// 16 ds-states live in registers per thread (no shuffles); B/C staged in LDS.
// GEMM/LN/conv/dt kernels unchanged from R2 (isolate the scan change).

#define BATCH 4
#define SEQL  4096
#define DMv   512
#define DIv   1024
#define DSv   16
#define DTRv  32
#define KCv   4
#define LCc   64      // chunk length
#define NG    64      // SEQL / LCc

// ---------------- LayerNorm: one 64-thread wave per row of 512 ----------------
__global__ __launch_bounds__(64) void ln_kernel(
    const float* __restrict__ in, const float* __restrict__ w,
    const float* __restrict__ b, float* __restrict__ out)
{
    const int row = blockIdx.x;
    const int t = threadIdx.x;
    const float* xr = in + (size_t)row * DMv;
    float4 v0 = *(const float4*)(xr + t * 4);
    float4 v1 = *(const float4*)(xr + 256 + t * 4);
    float s = v0.x + v0.y + v0.z + v0.w + v1.x + v1.y + v1.z + v1.w;
    float q = v0.x*v0.x + v0.y*v0.y + v0.z*v0.z + v0.w*v0.w
            + v1.x*v1.x + v1.y*v1.y + v1.z*v1.z + v1.w*v1.w;
    s += __shfl_xor(s, 1);  q += __shfl_xor(q, 1);
    s += __shfl_xor(s, 2);  q += __shfl_xor(q, 2);
    s += __shfl_xor(s, 4);  q += __shfl_xor(q, 4);
    s += __shfl_xor(s, 8);  q += __shfl_xor(q, 8);
    s += __shfl_xor(s, 16); q += __shfl_xor(q, 16);
    s += __shfl_xor(s, 32); q += __shfl_xor(q, 32);
    const float mean = s * (1.0f / DMv);
    const float var  = q * (1.0f / DMv) - mean * mean;
    const float rs   = rsqrtf(var + 1e-5f);

    float4 w0 = *(const float4*)(w + t * 4);
    float4 w1 = *(const float4*)(w + 256 + t * 4);
    float4 b0 = *(const float4*)(b + t * 4);
    float4 b1 = *(const float4*)(b + 256 + t * 4);
    float4 o0, o1;
    o0.x = (v0.x - mean) * rs * w0.x + b0.x;
    o0.y = (v0.y - mean) * rs * w0.y + b0.y;
    o0.z = (v0.z - mean) * rs * w0.z + b0.z;
    o0.w = (v0.w - mean) * rs * w0.w + b0.w;
    o1.x = (v1.x - mean) * rs * w1.x + b1.x;
    o1.y = (v1.y - mean) * rs * w1.y + b1.y;
    o1.z = (v1.z - mean) * rs * w1.z + b1.z;
    o1.w = (v1.w - mean) * rs * w1.w + b1.w;
    float* orow = out + (size_t)row * DMv;
    *(float4*)(orow + t * 4)       = o0;
    *(float4*)(orow + 256 + t * 4) = o1;
}

// ---------------- fp32 GEMM, C[M,N] = A[M,K] * W[N,K]^T  (both K-contiguous) --
__global__ __launch_bounds__(256) void sgemm_bt(
    const float* __restrict__ A, int lda,
    const float* __restrict__ W, int ldw,
    float* __restrict__ C, int ldc, int Kdim)
{
    __shared__ float As[16][68];
    __shared__ float Ws[16][68];
    const int t  = threadIdx.x;
    const int m0 = blockIdx.y * 64;
    const int n0 = blockIdx.x * 64;
    const int rr = t >> 2;
    const int kq = (t & 3) << 2;
    const float* Ap = A + (size_t)(m0 + rr) * lda + kq;
    const float* Wp = W + (size_t)(n0 + rr) * ldw + kq;
    const int tm = (t >> 4) << 2;
    const int tn = (t & 15) << 2;

    float acc[4][4];
#pragma unroll
    for (int i = 0; i < 4; i++)
#pragma unroll
        for (int j = 0; j < 4; j++) acc[i][j] = 0.0f;

    for (int k0 = 0; k0 < Kdim; k0 += 16) {
        __syncthreads();
        float4 av = *(const float4*)(Ap + k0);
        float4 wv = *(const float4*)(Wp + k0);
        As[kq + 0][rr] = av.x; As[kq + 1][rr] = av.y;
        As[kq + 2][rr] = av.z; As[kq + 3][rr] = av.w;
        Ws[kq + 0][rr] = wv.x; Ws[kq + 1][rr] = wv.y;
        Ws[kq + 2][rr] = wv.z; Ws[kq + 3][rr] = wv.w;
        __syncthreads();
#pragma unroll
        for (int k = 0; k < 16; k++) {
            float4 a4 = *(const float4*)&As[k][tm];
            float4 b4 = *(const float4*)&Ws[k][tn];
            float a[4] = {a4.x, a4.y, a4.z, a4.w};
            float bb[4] = {b4.x, b4.y, b4.z, b4.w};
#pragma unroll
            for (int i = 0; i < 4; i++)
#pragma unroll
                for (int j = 0; j < 4; j++) acc[i][j] += a[i] * bb[j];
        }
    }
    const int mb = m0 + tm;
    const int nb = n0 + tn;
#pragma unroll
    for (int i = 0; i < 4; i++) {
        float4 o = make_float4(acc[i][0], acc[i][1], acc[i][2], acc[i][3]);
        *(float4*)(C + (size_t)(mb + i) * ldc + nb) = o;
    }
}

// ---------------- depthwise causal conv(K=4) + bias + silu --------------------
__global__ __launch_bounds__(256) void conv_silu_kernel(
    const float* __restrict__ xz, const float* __restrict__ cw,
    const float* __restrict__ cb, float* __restrict__ xc)
{
    const int bl = blockIdx.x;
    const int l  = bl & (SEQL - 1);
    const int t  = threadIdx.x;
#pragma unroll
    for (int j = 0; j < 4; j++) {
        const int c = (j << 8) + t;
        float4 w4 = *(const float4*)(cw + c * 4);
        float wk[4] = {w4.x, w4.y, w4.z, w4.w};
        float acc = cb[c];
#pragma unroll
        for (int k = 0; k < KCv; k++) {
            const int lp = l - 3 + k;
            if (lp >= 0) {
                const long rowi = (long)bl + k - 3;
                acc += xz[(size_t)rowi * (2 * DIv) + c] * wk[k];
            }
        }
        const float sg = acc / (1.0f + __expf(-acc));
        xc[(size_t)bl * DIv + c] = sg;
    }
}

// ---------------- dt = softplus(dtr @ dt_w^T + dt_b) --------------------------
__global__ __launch_bounds__(256) void dtk_kernel(
    const float* __restrict__ dbl, const float* __restrict__ dt_w,
    const float* __restrict__ dt_b, float* __restrict__ dt)
{
    __shared__ float s_dtr[128][32];
    const int t  = threadIdx.x;
    const int r0 = blockIdx.x * 128;
    const int di = blockIdx.y * 256 + t;

    float w[32];
    const float4* wp = (const float4*)(dt_w + (size_t)di * DTRv);
#pragma unroll
    for (int j = 0; j < 8; j++) {
        float4 v = wp[j];
        w[j * 4 + 0] = v.x; w[j * 4 + 1] = v.y; w[j * 4 + 2] = v.z; w[j * 4 + 3] = v.w;
    }
    const float bias = dt_b[di];

    for (int e = t; e < 128 * 32; e += 256) {
        const int r = e >> 5, k = e & 31;
        s_dtr[r][k] = dbl[(size_t)(r0 + r) * 64 + k];
    }
    __syncthreads();

    for (int r = 0; r < 128; r++) {
        float acc = bias;
#pragma unroll
        for (int k = 0; k < 32; k++) acc += s_dtr[r][k] * w[k];
        const float sp = (acc > 20.0f) ? acc : log1pf(__expf(acc));
        dt[(size_t)(r0 + r) * DIv + di] = sp;
    }
}

// ---------------- chunked scan, phase 1: local P & S per chunk ----------------
// blockIdx.x = ((b*NG + g)*4 + dq); 256 threads over di-quarter.
// Pbuf/Sbuf layout: [b][g][ds][di]  (di contiguous -> coalesced).
__global__ __launch_bounds__(256) void scan_p1(
    const float* __restrict__ dt, const float* __restrict__ xc,
    const float* __restrict__ dbl, const float* __restrict__ A_log,
    float* __restrict__ Pbuf, float* __restrict__ Sbuf)
{
    const int bid = blockIdx.x;
    const int dq  = bid & 3;
    const int g   = (bid >> 2) & (NG - 1);
    const int b   = bid >> 8;
    const int di  = (dq << 8) + threadIdx.x;

    __shared__ float sB[LCc][DSv];
    const float* blp = dbl + ((size_t)b * SEQL + (size_t)g * LCc) * 64;
    for (int e = threadIdx.x; e < LCc * DSv; e += 256) {
        const int l = e >> 4, s = e & 15;
        sB[l][s] = blp[l * 64 + 32 + s];
    }
    __syncthreads();

    float Areg[DSv], P[DSv], S[DSv];
#pragma unroll
    for (int s = 0; s < DSv; s++) {
        Areg[s] = -__expf(A_log[di * DSv + s]);
        P[s] = 1.0f;
        S[s] = 0.0f;
    }

    const float* dtp = dt + ((size_t)b * SEQL + (size_t)g * LCc) * DIv + di;
    const float* xp  = xc + ((size_t)b * SEQL + (size_t)g * LCc) * DIv + di;
#pragma unroll 2
    for (int l = 0; l < LCc; l++) {
        const float dtv = dtp[(size_t)l * DIv];
        const float xv  = xp[(size_t)l * DIv];
        const float u   = dtv * xv;
#pragma unroll
        for (int s = 0; s < DSv; s++) {
            const float a = __expf(dtv * Areg[s]);
            P[s] *= a;
            S[s] = S[s] * a + u * sB[l][s];
        }
    }

    float* pp = Pbuf + (((size_t)b * NG + g) * DSv) * DIv + di;
    float* sp = Sbuf + (((size_t)b * NG + g) * DSv) * DIv + di;
#pragma unroll
    for (int s = 0; s < DSv; s++) {
        pp[(size_t)s * DIv] = P[s];
        sp[(size_t)s * DIv] = S[s];
    }
}

// ---------------- chunked scan, phase 2: combine across chunks ----------------
// One thread per (b, ds, di). Overwrites Sbuf[g] with the seed state h_in[g].
__global__ __launch_bounds__(256) void scan_p2(
    const float* __restrict__ Pbuf, float* __restrict__ Sbuf)
{
    const int idx = blockIdx.x * 256 + threadIdx.x;   // b*16384 + s*1024 + di
    const int di  = idx & (DIv - 1);
    const int s   = (idx >> 10) & 15;
    const int b   = idx >> 14;
    const size_t gstride = (size_t)DSv * DIv;
    size_t base = (((size_t)b * NG) * DSv + s) * DIv + di;
    float h = 0.0f;
    for (int g = 0; g < NG; g++) {
        const float P = Pbuf[base];
        const float S = Sbuf[base];
        Sbuf[base] = h;          // seed for chunk g
        h = P * h + S;           // state after chunk g
        base += gstride;
    }
}

// ---------------- chunked scan, phase 3: seeded local scan + gate -------------
// Reads z from xz[...,DI:], writes gated y into xz[...,:DI].
__global__ __launch_bounds__(256) void scan_p3(
    const float* __restrict__ dt, const float* __restrict__ xc,
    const float* __restrict__ dbl, const float* __restrict__ A_log,
    const float* __restrict__ Dp, const float* __restrict__ Sbuf,
    float* __restrict__ xzbuf)
{
    const int bid = blockIdx.x;
    const int dq  = bid & 3;
    const int g   = (bid >> 2) & (NG - 1);
    const int b   = bid >> 8;
    const int di  = (dq << 8) + threadIdx.x;

    __shared__ float sB[LCc][DSv];
    __shared__ float sC[LCc][DSv];
    const float* blp = dbl + ((size_t)b * SEQL + (size_t)g * LCc) * 64;
    for (int e = threadIdx.x; e < LCc * DSv; e += 256) {
        const int l = e >> 4, s = e & 15;
        sB[l][s] = blp[l * 64 + 32 + s];
        sC[l][s] = blp[l * 64 + 48 + s];
    }
    __syncthreads();

    float Areg[DSv], h[DSv];
    const float* seedp = Sbuf + (((size_t)b * NG + g) * DSv) * DIv + di;
#pragma unroll
    for (int s = 0; s < DSv; s++) {
        Areg[s] = -__expf(A_log[di * DSv + s]);
        h[s] = seedp[(size_t)s * DIv];
    }
    const float Dv = Dp[di];

    const float* dtp = dt + ((size_t)b * SEQL + (size_t)g * LCc) * DIv + di;
    const float* xp  = xc + ((size_t)b * SEQL + (size_t)g * LCc) * DIv + di;
    float* zgp = xzbuf + ((size_t)b * SEQL + (size_t)g * LCc) * (2 * DIv);

#pragma unroll 2
    for (int l = 0; l < LCc; l++) {
        const float dtv = dtp[(size_t)l * DIv];
        const float xv  = xp[(size_t)l * DIv];
        const float zv  = zgp[(size_t)l * (2 * DIv) + DIv + di];
        const float u   = dtv * xv;
        float y = 0.0f;
#pragma unroll
        for (int s = 0; s < DSv; s++) {
            const float a = __expf(dtv * Areg[s]);
            h[s] = h[s] * a + u * sB[l][s];
            y += h[s] * sC[l][s];
        }
        y += xv * Dv;
        const float sg = zv / (1.0f + __expf(-zv));
        zgp[(size_t)l * (2 * DIv) + di] = y * sg;
    }
}

extern "C" void kernel_launch(void* const* d_in, const int* in_sizes, int n_in,
                              void* d_out, int out_size, void* d_ws, size_t ws_size,
                              hipStream_t stream)
{
    const float* x       = (const float*)d_in[0];
    const float* ln_w    = (const float*)d_in[1];
    const float* ln_b    = (const float*)d_in[2];
    const float* in_w    = (const float*)d_in[3];
    const float* conv_w  = (const float*)d_in[4];
    const float* conv_b  = (const float*)d_in[5];
    const float* xproj_w = (const float*)d_in[6];
    const float* dt_w    = (const float*)d_in[7];
    const float* dt_b    = (const float*)d_in[8];
    const float* A_log   = (const float*)d_in[9];
    const float* Dvec    = (const float*)d_in[10];
    const float* out_w   = (const float*)d_in[11];
    float* out = (float*)d_out;

    // Per-batch scratch floats: hn DM + xz 2DI + xc DI + dbl 64 + dt DI per row,
    // plus P/S chunk buffers 2 * NG*DS*DI.
    const size_t perb = ((size_t)SEQL * (DMv + 2 * DIv + DIv + 64 + DIv)
                         + 2 * (size_t)NG * DSv * DIv) * sizeof(float);
    const int CB = (ws_size >= 4 * perb) ? 4 : (ws_size >= 2 * perb) ? 2 : 1;

    for (int i = 0; i < 2; i++) {
        const float* hin_base = (i == 0) ? x : out;
        for (int c0 = 0; c0 < BATCH; c0 += CB) {
            const int MR = CB * SEQL;
            float* ws   = (float*)d_ws;
            float* hn   = ws;                            // MR*DM
            float* xz   = hn   + (size_t)MR * DMv;       // MR*2*DI
            float* xc   = xz   + (size_t)MR * 2 * DIv;   // MR*DI
            float* dbl  = xc   + (size_t)MR * DIv;       // MR*64
            float* dtb  = dbl  + (size_t)MR * 64;        // MR*DI
            float* Pbuf = dtb  + (size_t)MR * DIv;       // CB*NG*DS*DI
            float* Sbuf = Pbuf + (size_t)CB * NG * DSv * DIv;
            const size_t row0 = (size_t)c0 * SEQL;

            ln_kernel<<<MR, 64, 0, stream>>>(
                hin_base + row0 * DMv, ln_w + i * DMv, ln_b + i * DMv, hn);
            sgemm_bt<<<dim3(2 * DIv / 64, MR / 64), 256, 0, stream>>>(
                hn, DMv, in_w + (size_t)i * 2 * DIv * DMv, DMv, xz, 2 * DIv, DMv);
            conv_silu_kernel<<<MR, 256, 0, stream>>>(
                xz, conv_w + i * DIv * KCv, conv_b + i * DIv, xc);
            sgemm_bt<<<dim3(1, MR / 64), 256, 0, stream>>>(
                xc, DIv, xproj_w + (size_t)i * 64 * DIv, DIv, dbl, 64, DIv);
            dtk_kernel<<<dim3(MR / 128, DIv / 256), 256, 0, stream>>>(
                dbl, dt_w + (size_t)i * DIv * DTRv, dt_b + i * DIv, dtb);
            scan_p1<<<CB * NG * 4, 256, 0, stream>>>(
                dtb, xc, dbl, A_log + (size_t)i * DIv * DSv, Pbuf, Sbuf);
            scan_p2<<<CB * 64, 256, 0, stream>>>(Pbuf, Sbuf);
            scan_p3<<<CB * NG * 4, 256, 0, stream>>>(
                dtb, xc, dbl, A_log + (size_t)i * DIv * DSv, Dvec + i * DIv, Sbuf, xz);
            sgemm_bt<<<dim3(DMv / 64, MR / 64), 256, 0, stream>>>(
                xz, 2 * DIv, out_w + (size_t)i * DMv * DIv, DIv, out + row0 * DMv, DMv, DIv);
        }
    }
}

// Round 4
// 1350.141 us; speedup vs baseline: 4.5245x; 1.8469x over previous
//
#include <hip/hip_runtime.h>
#include <hip/hip_bf16.h>
#include <cstdint>

// mamba_model: DEPTH=2, B=4, L=4096, DM=512, DI=1024, DS=16, DTR=32, K=4
// Round 4: in-proj & out-proj GEMMs -> bf16 MFMA (m97 structure: 128x128 tile,
// BK=32, global_load_lds width-16, mfma_f32_16x16x32_bf16, 4 waves x 4x4 tiles)
// with XOR-swizzled LDS quarters for conflict-free ds_read_b128.
// Scan/conv/LN-stats/x-proj/dt stay fp32 (dt feeds an exponent). Gated y is
// written bf16 into the dead xq half of xz (lda=4096 bf16) -> perb unchanged
// enough that CB=2 still fits (R3 proved ws >= 169.9MB; need 164.6MB).

#define BATCH 4
#define SEQL  4096
#define DMv   512
#define DIv   1024
#define DSv   16
#define DTRv  32
#define KCv   4
#define LCc   64
#define NG    64

typedef __attribute__((ext_vector_type(8))) short short8;
typedef __attribute__((ext_vector_type(4))) float f32x4;

__device__ __forceinline__ unsigned short f2bf(float f) {
    unsigned int u = __builtin_bit_cast(unsigned int, f);
    u += 0x7FFFu + ((u >> 16) & 1u);          // round-to-nearest-even
    return (unsigned short)(u >> 16);
}

// ---------------- LayerNorm -> bf16 out: one wave per row of 512 --------------
__global__ __launch_bounds__(64) void ln_bf_kernel(
    const float* __restrict__ in, const float* __restrict__ w,
    const float* __restrict__ b, unsigned short* __restrict__ out)
{
    const int row = blockIdx.x;
    const int t = threadIdx.x;
    const float* xr = in + (size_t)row * DMv;
    float4 v0 = *(const float4*)(xr + t * 4);
    float4 v1 = *(const float4*)(xr + 256 + t * 4);
    float s = v0.x + v0.y + v0.z + v0.w + v1.x + v1.y + v1.z + v1.w;
    float q = v0.x*v0.x + v0.y*v0.y + v0.z*v0.z + v0.w*v0.w
            + v1.x*v1.x + v1.y*v1.y + v1.z*v1.z + v1.w*v1.w;
    s += __shfl_xor(s, 1);  q += __shfl_xor(q, 1);
    s += __shfl_xor(s, 2);  q += __shfl_xor(q, 2);
    s += __shfl_xor(s, 4);  q += __shfl_xor(q, 4);
    s += __shfl_xor(s, 8);  q += __shfl_xor(q, 8);
    s += __shfl_xor(s, 16); q += __shfl_xor(q, 16);
    s += __shfl_xor(s, 32); q += __shfl_xor(q, 32);
    const float mean = s * (1.0f / DMv);
    const float var  = q * (1.0f / DMv) - mean * mean;
    const float rs   = rsqrtf(var + 1e-5f);

    float4 w0 = *(const float4*)(w + t * 4);
    float4 w1 = *(const float4*)(w + 256 + t * 4);
    float4 b0 = *(const float4*)(b + t * 4);
    float4 b1 = *(const float4*)(b + 256 + t * 4);
    ushort4 o0, o1;
    o0.x = f2bf((v0.x - mean) * rs * w0.x + b0.x);
    o0.y = f2bf((v0.y - mean) * rs * w0.y + b0.y);
    o0.z = f2bf((v0.z - mean) * rs * w0.z + b0.z);
    o0.w = f2bf((v0.w - mean) * rs * w0.w + b0.w);
    o1.x = f2bf((v1.x - mean) * rs * w1.x + b1.x);
    o1.y = f2bf((v1.y - mean) * rs * w1.y + b1.y);
    o1.z = f2bf((v1.z - mean) * rs * w1.z + b1.z);
    o1.w = f2bf((v1.w - mean) * rs * w1.w + b1.w);
    unsigned short* orow = out + (size_t)row * DMv;
    *(ushort4*)(orow + t * 4)       = o0;
    *(ushort4*)(orow + 256 + t * 4) = o1;
}

// ---------------- fp32 -> bf16 weight conversion ------------------------------
__global__ __launch_bounds__(256) void w2bf_kernel(
    const float* __restrict__ in, unsigned short* __restrict__ out, int n)
{
    const int i = (blockIdx.x * 256 + threadIdx.x) * 4;
    if (i + 3 < n) {
        float4 v = *(const float4*)(in + i);
        ushort4 o;
        o.x = f2bf(v.x); o.y = f2bf(v.y); o.z = f2bf(v.z); o.w = f2bf(v.w);
        *(ushort4*)(out + i) = o;
    }
}

// ---------------- bf16 MFMA GEMM: C[M,N]fp32 = A[M,K]bf16 * W[N,K]bf16^T ------
// 128x128 tile, BK=32, 256 threads = 4 waves (2x2), each wave 4x4 16x16 tiles.
// LDS quarters XOR-swizzled by (row>>1)&3: staging permutes the global column,
// fragment reads un-permute -> ds_read_b128 lands 2-way max (free, m136).
__global__ __launch_bounds__(256) void bgemm_bt(
    const unsigned short* __restrict__ A, int lda,
    const unsigned short* __restrict__ W, int ldw,
    float* __restrict__ C, int ldc, int Kdim)
{
    __shared__ unsigned short Alds[128 * 32];
    __shared__ unsigned short Blds[128 * 32];
    const int t    = threadIdx.x;
    const int lane = t & 63;
    const int wv   = t >> 6;             // 0..3
    const int wm   = wv & 1;             // wave tile (2x2 of 64x64)
    const int wn   = wv >> 1;
    const int m0 = blockIdx.y * 128, n0 = blockIdx.x * 128;

    const int srow = lane >> 2;                      // 0..15 staging row
    const int sq   = (lane & 3) ^ ((srow >> 1) & 3); // swizzled global quarter
    const unsigned short* Ag = A + (size_t)(m0 + wv * 16 + srow) * lda + sq * 8;
    const unsigned short* Wg = W + (size_t)(n0 + wv * 16 + srow) * ldw + sq * 8;

    f32x4 acc[4][4];
#pragma unroll
    for (int mi = 0; mi < 4; mi++)
#pragma unroll
        for (int ni = 0; ni < 4; ni++) acc[mi][ni] = (f32x4)0.0f;

    const int r = lane & 15;
    const int q = lane >> 4;

    for (int k0 = 0; k0 < Kdim; k0 += 32) {
        __syncthreads();
#pragma unroll
        for (int j = 0; j < 2; j++) {
            __builtin_amdgcn_global_load_lds(
                (const __attribute__((address_space(1))) unsigned int*)(Ag + (size_t)j * 64 * lda + k0),
                (__attribute__((address_space(3))) unsigned int*)(Alds + (wv * 16 + j * 64) * 32),
                16, 0, 0);
            __builtin_amdgcn_global_load_lds(
                (const __attribute__((address_space(1))) unsigned int*)(Wg + (size_t)j * 64 * ldw + k0),
                (__attribute__((address_space(3))) unsigned int*)(Blds + (wv * 16 + j * 64) * 32),
                16, 0, 0);
        }
        __syncthreads();

        short8 af[4], bf[4];
#pragma unroll
        for (int mi = 0; mi < 4; mi++) {
            const int rr = wm * 64 + mi * 16 + r;
            const int qq = q ^ ((r >> 1) & 3);
            af[mi] = *(const short8*)(Alds + rr * 32 + qq * 8);
        }
#pragma unroll
        for (int ni = 0; ni < 4; ni++) {
            const int rr = wn * 64 + ni * 16 + r;
            const int qq = q ^ ((r >> 1) & 3);
            bf[ni] = *(const short8*)(Blds + rr * 32 + qq * 8);
        }
#pragma unroll
        for (int mi = 0; mi < 4; mi++)
#pragma unroll
            for (int ni = 0; ni < 4; ni++)
                acc[mi][ni] = __builtin_amdgcn_mfma_f32_16x16x32_bf16(
                    af[mi], bf[ni], acc[mi][ni], 0, 0, 0);
    }

#pragma unroll
    for (int mi = 0; mi < 4; mi++)
#pragma unroll
        for (int ni = 0; ni < 4; ni++) {
            const int row = m0 + wm * 64 + mi * 16 + q * 4;
            const int col = n0 + wn * 64 + ni * 16 + r;
#pragma unroll
            for (int rg = 0; rg < 4; rg++)
                C[(size_t)(row + rg) * ldc + col] = acc[mi][ni][rg];
        }
}

// ---------------- fp32 GEMM (kept for x-proj, N=64) ---------------------------
__global__ __launch_bounds__(256) void sgemm_bt(
    const float* __restrict__ A, int lda,
    const float* __restrict__ W, int ldw,
    float* __restrict__ C, int ldc, int Kdim)
{
    __shared__ float As[16][68];
    __shared__ float Ws[16][68];
    const int t  = threadIdx.x;
    const int m0 = blockIdx.y * 64;
    const int n0 = blockIdx.x * 64;
    const int rr = t >> 2;
    const int kq = (t & 3) << 2;
    const float* Ap = A + (size_t)(m0 + rr) * lda + kq;
    const float* Wp = W + (size_t)(n0 + rr) * ldw + kq;
    const int tm = (t >> 4) << 2;
    const int tn = (t & 15) << 2;

    float acc[4][4];
#pragma unroll
    for (int i = 0; i < 4; i++)
#pragma unroll
        for (int j = 0; j < 4; j++) acc[i][j] = 0.0f;

    for (int k0 = 0; k0 < Kdim; k0 += 16) {
        __syncthreads();
        float4 av = *(const float4*)(Ap + k0);
        float4 wv = *(const float4*)(Wp + k0);
        As[kq + 0][rr] = av.x; As[kq + 1][rr] = av.y;
        As[kq + 2][rr] = av.z; As[kq + 3][rr] = av.w;
        Ws[kq + 0][rr] = wv.x; Ws[kq + 1][rr] = wv.y;
        Ws[kq + 2][rr] = wv.z; Ws[kq + 3][rr] = wv.w;
        __syncthreads();
#pragma unroll
        for (int k = 0; k < 16; k++) {
            float4 a4 = *(const float4*)&As[k][tm];
            float4 b4 = *(const float4*)&Ws[k][tn];
            float a[4] = {a4.x, a4.y, a4.z, a4.w};
            float bb[4] = {b4.x, b4.y, b4.z, b4.w};
#pragma unroll
            for (int i = 0; i < 4; i++)
#pragma unroll
                for (int j = 0; j < 4; j++) acc[i][j] += a[i] * bb[j];
        }
    }
    const int mb = m0 + tm;
    const int nb = n0 + tn;
#pragma unroll
    for (int i = 0; i < 4; i++) {
        float4 o = make_float4(acc[i][0], acc[i][1], acc[i][2], acc[i][3]);
        *(float4*)(C + (size_t)(mb + i) * ldc + nb) = o;
    }
}

// ---------------- depthwise causal conv(K=4) + bias + silu --------------------
__global__ __launch_bounds__(256) void conv_silu_kernel(
    const float* __restrict__ xz, const float* __restrict__ cw,
    const float* __restrict__ cb, float* __restrict__ xc)
{
    const int bl = blockIdx.x;
    const int l  = bl & (SEQL - 1);
    const int t  = threadIdx.x;
#pragma unroll
    for (int j = 0; j < 4; j++) {
        const int c = (j << 8) + t;
        float4 w4 = *(const float4*)(cw + c * 4);
        float wk[4] = {w4.x, w4.y, w4.z, w4.w};
        float acc = cb[c];
#pragma unroll
        for (int k = 0; k < KCv; k++) {
            const int lp = l - 3 + k;
            if (lp >= 0) {
                const long rowi = (long)bl + k - 3;
                acc += xz[(size_t)rowi * (2 * DIv) + c] * wk[k];
            }
        }
        const float sg = acc / (1.0f + __expf(-acc));
        xc[(size_t)bl * DIv + c] = sg;
    }
}

// ---------------- dt = softplus(dtr @ dt_w^T + dt_b) --------------------------
__global__ __launch_bounds__(256) void dtk_kernel(
    const float* __restrict__ dbl, const float* __restrict__ dt_w,
    const float* __restrict__ dt_b, float* __restrict__ dt)
{
    __shared__ float s_dtr[128][32];
    const int t  = threadIdx.x;
    const int r0 = blockIdx.x * 128;
    const int di = blockIdx.y * 256 + t;

    float w[32];
    const float4* wp = (const float4*)(dt_w + (size_t)di * DTRv);
#pragma unroll
    for (int j = 0; j < 8; j++) {
        float4 v = wp[j];
        w[j * 4 + 0] = v.x; w[j * 4 + 1] = v.y; w[j * 4 + 2] = v.z; w[j * 4 + 3] = v.w;
    }
    const float bias = dt_b[di];

    for (int e = t; e < 128 * 32; e += 256) {
        const int r = e >> 5, k = e & 31;
        s_dtr[r][k] = dbl[(size_t)(r0 + r) * 64 + k];
    }
    __syncthreads();

    for (int r = 0; r < 128; r++) {
        float acc = bias;
#pragma unroll
        for (int k = 0; k < 32; k++) acc += s_dtr[r][k] * w[k];
        const float sp = (acc > 20.0f) ? acc : log1pf(__expf(acc));
        dt[(size_t)(r0 + r) * DIv + di] = sp;
    }
}

// ---------------- chunked scan, phase 1 ---------------------------------------
__global__ __launch_bounds__(256) void scan_p1(
    const float* __restrict__ dt, const float* __restrict__ xc,
    const float* __restrict__ dbl, const float* __restrict__ A_log,
    float* __restrict__ Pbuf, float* __restrict__ Sbuf)
{
    const int bid = blockIdx.x;
    const int dq  = bid & 3;
    const int g   = (bid >> 2) & (NG - 1);
    const int b   = bid >> 8;
    const int di  = (dq << 8) + threadIdx.x;

    __shared__ float sB[LCc][DSv];
    const float* blp = dbl + ((size_t)b * SEQL + (size_t)g * LCc) * 64;
    for (int e = threadIdx.x; e < LCc * DSv; e += 256) {
        const int l = e >> 4, s = e & 15;
        sB[l][s] = blp[l * 64 + 32 + s];
    }
    __syncthreads();

    float Areg[DSv], P[DSv], S[DSv];
#pragma unroll
    for (int s = 0; s < DSv; s++) {
        Areg[s] = -__expf(A_log[di * DSv + s]);
        P[s] = 1.0f;
        S[s] = 0.0f;
    }

    const float* dtp = dt + ((size_t)b * SEQL + (size_t)g * LCc) * DIv + di;
    const float* xp  = xc + ((size_t)b * SEQL + (size_t)g * LCc) * DIv + di;
#pragma unroll 2
    for (int l = 0; l < LCc; l++) {
        const float dtv = dtp[(size_t)l * DIv];
        const float xv  = xp[(size_t)l * DIv];
        const float u   = dtv * xv;
#pragma unroll
        for (int s = 0; s < DSv; s++) {
            const float a = __expf(dtv * Areg[s]);
            P[s] *= a;
            S[s] = S[s] * a + u * sB[l][s];
        }
    }

    float* pp = Pbuf + (((size_t)b * NG + g) * DSv) * DIv + di;
    float* sp = Sbuf + (((size_t)b * NG + g) * DSv) * DIv + di;
#pragma unroll
    for (int s = 0; s < DSv; s++) {
        pp[(size_t)s * DIv] = P[s];
        sp[(size_t)s * DIv] = S[s];
    }
}

// ---------------- chunked scan, phase 2 ---------------------------------------
__global__ __launch_bounds__(256) void scan_p2(
    const float* __restrict__ Pbuf, float* __restrict__ Sbuf)
{
    const int idx = blockIdx.x * 256 + threadIdx.x;
    const int di  = idx & (DIv - 1);
    const int s   = (idx >> 10) & 15;
    const int b   = idx >> 14;
    const size_t gstride = (size_t)DSv * DIv;
    size_t base = (((size_t)b * NG) * DSv + s) * DIv + di;
    float h = 0.0f;
    for (int g = 0; g < NG; g++) {
        const float P = Pbuf[base];
        const float S = Sbuf[base];
        Sbuf[base] = h;
        h = P * h + S;
        base += gstride;
    }
}

// ---------------- chunked scan, phase 3: seeded scan + gate -> bf16 y ---------
// Reads z (fp32) from xz[...,DI:]; writes gated y as bf16 into the first
// 2048 bytes of each xz row (dead xq half). lda for out-proj = 4096 bf16.
__global__ __launch_bounds__(256) void scan_p3(
    const float* __restrict__ dt, const float* __restrict__ xc,
    const float* __restrict__ dbl, const float* __restrict__ A_log,
    const float* __restrict__ Dp, const float* __restrict__ Sbuf,
    float* __restrict__ xzbuf)
{
    const int bid = blockIdx.x;
    const int dq  = bid & 3;
    const int g   = (bid >> 2) & (NG - 1);
    const int b   = bid >> 8;
    const int di  = (dq << 8) + threadIdx.x;

    __shared__ float sB[LCc][DSv];
    __shared__ float sC[LCc][DSv];
    const float* blp = dbl + ((size_t)b * SEQL + (size_t)g * LCc) * 64;
    for (int e = threadIdx.x; e < LCc * DSv; e += 256) {
        const int l = e >> 4, s = e & 15;
        sB[l][s] = blp[l * 64 + 32 + s];
        sC[l][s] = blp[l * 64 + 48 + s];
    }
    __syncthreads();

    float Areg[DSv], h[DSv];
    const float* seedp = Sbuf + (((size_t)b * NG + g) * DSv) * DIv + di;
#pragma unroll
    for (int s = 0; s < DSv; s++) {
        Areg[s] = -__expf(A_log[di * DSv + s]);
        h[s] = seedp[(size_t)s * DIv];
    }
    const float Dv = Dp[di];

    const float* dtp = dt + ((size_t)b * SEQL + (size_t)g * LCc) * DIv + di;
    const float* xp  = xc + ((size_t)b * SEQL + (size_t)g * LCc) * DIv + di;
    const size_t row0 = (size_t)b * SEQL + (size_t)g * LCc;
    const float* zp = xzbuf + row0 * (2 * DIv) + DIv + di;
    unsigned short* yb = (unsigned short*)xzbuf;   // bf16 rows, stride 4096

#pragma unroll 2
    for (int l = 0; l < LCc; l++) {
        const float dtv = dtp[(size_t)l * DIv];
        const float xv  = xp[(size_t)l * DIv];
        const float zv  = zp[(size_t)l * (2 * DIv)];
        const float u   = dtv * xv;
        float y = 0.0f;
#pragma unroll
        for (int s = 0; s < DSv; s++) {
            const float a = __expf(dtv * Areg[s]);
            h[s] = h[s] * a + u * sB[l][s];
            y += h[s] * sC[l][s];
        }
        y += xv * Dv;
        const float sg = zv / (1.0f + __expf(-zv));
        yb[(row0 + l) * (size_t)4096 + di] = f2bf(y * sg);
    }
}

extern "C" void kernel_launch(void* const* d_in, const int* in_sizes, int n_in,
                              void* d_out, int out_size, void* d_ws, size_t ws_size,
                              hipStream_t stream)
{
    const float* x       = (const float*)d_in[0];
    const float* ln_w    = (const float*)d_in[1];
    const float* ln_b    = (const float*)d_in[2];
    const float* in_w    = (const float*)d_in[3];
    const float* conv_w  = (const float*)d_in[4];
    const float* conv_b  = (const float*)d_in[5];
    const float* xproj_w = (const float*)d_in[6];
    const float* dt_w    = (const float*)d_in[7];
    const float* dt_b    = (const float*)d_in[8];
    const float* A_log   = (const float*)d_in[9];
    const float* Dvec    = (const float*)d_in[10];
    const float* out_w   = (const float*)d_in[11];
    float* out = (float*)d_out;

    // Fixed weight area (bf16): in_w 2048x512, out_w 512x1024.
    const size_t wfix = (size_t)(2 * DIv * DMv + DMv * DIv) * 2;   // bytes
    // Per-batch bytes: hnbf + xz + xc + dbl + dt + P/S
    const size_t perb = (size_t)SEQL * (DMv * 2 + 2 * DIv * 4 + DIv * 4 + 64 * 4 + DIv * 4)
                      + 2 * (size_t)NG * DSv * DIv * 4;
    const int CB = (ws_size >= wfix + 4 * perb) ? 4
                 : (ws_size >= wfix + 2 * perb) ? 2 : 1;

    char* wsb = (char*)d_ws;
    unsigned short* inwbf  = (unsigned short*)wsb;
    unsigned short* outwbf = inwbf + (size_t)2 * DIv * DMv;
    char* chunk0 = wsb + wfix;

    for (int i = 0; i < 2; i++) {
        const float* hin_base = (i == 0) ? x : out;
        w2bf_kernel<<<(2 * DIv * DMv) / 1024, 256, 0, stream>>>(
            in_w + (size_t)i * 2 * DIv * DMv, inwbf, 2 * DIv * DMv);
        w2bf_kernel<<<(DMv * DIv) / 1024, 256, 0, stream>>>(
            out_w + (size_t)i * DMv * DIv, outwbf, DMv * DIv);

        for (int c0 = 0; c0 < BATCH; c0 += CB) {
            const int MR = CB * SEQL;
            char* p = chunk0;
            unsigned short* hnbf = (unsigned short*)p; p += (size_t)MR * DMv * 2;
            float* xz   = (float*)p; p += (size_t)MR * 2 * DIv * 4;
            float* xc   = (float*)p; p += (size_t)MR * DIv * 4;
            float* dbl  = (float*)p; p += (size_t)MR * 64 * 4;
            float* dtb  = (float*)p; p += (size_t)MR * DIv * 4;
            float* Pbuf = (float*)p; p += (size_t)CB * NG * DSv * DIv * 4;
            float* Sbuf = (float*)p;
            const size_t row0 = (size_t)c0 * SEQL;

            ln_bf_kernel<<<MR, 64, 0, stream>>>(
                hin_base + row0 * DMv, ln_w + i * DMv, ln_b + i * DMv, hnbf);
            // in-proj: (MRx512)bf16 * (2048x512)bf16^T -> xz fp32 (MRx2048)
            bgemm_bt<<<dim3(2 * DIv / 128, MR / 128), 256, 0, stream>>>(
                hnbf, DMv, inwbf, DMv, xz, 2 * DIv, DMv);
            conv_silu_kernel<<<MR, 256, 0, stream>>>(
                xz, conv_w + i * DIv * KCv, conv_b + i * DIv, xc);
            // x-proj: fp32 (MRx1024) * (64x1024)^T -> dbl
            sgemm_bt<<<dim3(1, MR / 64), 256, 0, stream>>>(
                xc, DIv, xproj_w + (size_t)i * 64 * DIv, DIv, dbl, 64, DIv);
            dtk_kernel<<<dim3(MR / 128, DIv / 256), 256, 0, stream>>>(
                dbl, dt_w + (size_t)i * DIv * DTRv, dt_b + i * DIv, dtb);
            scan_p1<<<CB * NG * 4, 256, 0, stream>>>(
                dtb, xc, dbl, A_log + (size_t)i * DIv * DSv, Pbuf, Sbuf);
            scan_p2<<<CB * 64, 256, 0, stream>>>(Pbuf, Sbuf);
            scan_p3<<<CB * NG * 4, 256, 0, stream>>>(
                dtb, xc, dbl, A_log + (size_t)i * DIv * DSv, Dvec + i * DIv, Sbuf, xz);
            // out-proj: y bf16 (in xz, lda=4096) * (512x1024)bf16^T -> out fp32
            bgemm_bt<<<dim3(DMv / 128, MR / 128), 256, 0, stream>>>(
                (const unsigned short*)xz, 2 * (2 * DIv), outwbf, DIv, out + row0 * DMv, DMv, DIv);
        }
    }
}

// Round 5
// 1212.609 us; speedup vs baseline: 5.0376x; 1.1134x over previous
//
#include <hip/hip_runtime.h>
#include <hip/hip_bf16.h>
#include <cstdint>

// mamba_model: DEPTH=2, B=4, L=4096, DM=512, DI=1024, DS=16, DTR=32, K=4
// Round 5: fix the two low-occupancy fp32 kernels found in R4's profile.
//  - dtk: was 70us/dispatch @ 9.8% occupancy, VGPR=32 (w[] rematerialized).
//    Rewritten: dtr row read via wave-uniform address (-> s_load broadcast),
//    w row in 8 float4 VGPRs, 64 rows/block, 512 blocks (2/CU).
//  - x-proj: was grid (1,128) = half the chip idle. Now split-K=4 into Pbuf
//    (dead until scan_p1; exactly MR*64*4 floats at every CB) + tiny reduce.
// bgemm (bf16 MFMA in/out-proj), conv, LN, scan unchanged from R4 (passed,
// absmax 2.44e-4).

#define BATCH 4
#define SEQL  4096
#define DMv   512
#define DIv   1024
#define DSv   16
#define DTRv  32
#define KCv   4
#define LCc   64
#define NG    64

typedef __attribute__((ext_vector_type(8))) short short8;
typedef __attribute__((ext_vector_type(4))) float f32x4;

__device__ __forceinline__ unsigned short f2bf(float f) {
    unsigned int u = __builtin_bit_cast(unsigned int, f);
    u += 0x7FFFu + ((u >> 16) & 1u);          // round-to-nearest-even
    return (unsigned short)(u >> 16);
}

// ---------------- LayerNorm -> bf16 out: one wave per row of 512 --------------
__global__ __launch_bounds__(64) void ln_bf_kernel(
    const float* __restrict__ in, const float* __restrict__ w,
    const float* __restrict__ b, unsigned short* __restrict__ out)
{
    const int row = blockIdx.x;
    const int t = threadIdx.x;
    const float* xr = in + (size_t)row * DMv;
    float4 v0 = *(const float4*)(xr + t * 4);
    float4 v1 = *(const float4*)(xr + 256 + t * 4);
    float s = v0.x + v0.y + v0.z + v0.w + v1.x + v1.y + v1.z + v1.w;
    float q = v0.x*v0.x + v0.y*v0.y + v0.z*v0.z + v0.w*v0.w
            + v1.x*v1.x + v1.y*v1.y + v1.z*v1.z + v1.w*v1.w;
    s += __shfl_xor(s, 1);  q += __shfl_xor(q, 1);
    s += __shfl_xor(s, 2);  q += __shfl_xor(q, 2);
    s += __shfl_xor(s, 4);  q += __shfl_xor(q, 4);
    s += __shfl_xor(s, 8);  q += __shfl_xor(q, 8);
    s += __shfl_xor(s, 16); q += __shfl_xor(q, 16);
    s += __shfl_xor(s, 32); q += __shfl_xor(q, 32);
    const float mean = s * (1.0f / DMv);
    const float var  = q * (1.0f / DMv) - mean * mean;
    const float rs   = rsqrtf(var + 1e-5f);

    float4 w0 = *(const float4*)(w + t * 4);
    float4 w1 = *(const float4*)(w + 256 + t * 4);
    float4 b0 = *(const float4*)(b + t * 4);
    float4 b1 = *(const float4*)(b + 256 + t * 4);
    ushort4 o0, o1;
    o0.x = f2bf((v0.x - mean) * rs * w0.x + b0.x);
    o0.y = f2bf((v0.y - mean) * rs * w0.y + b0.y);
    o0.z = f2bf((v0.z - mean) * rs * w0.z + b0.z);
    o0.w = f2bf((v0.w - mean) * rs * w0.w + b0.w);
    o1.x = f2bf((v1.x - mean) * rs * w1.x + b1.x);
    o1.y = f2bf((v1.y - mean) * rs * w1.y + b1.y);
    o1.z = f2bf((v1.z - mean) * rs * w1.z + b1.z);
    o1.w = f2bf((v1.w - mean) * rs * w1.w + b1.w);
    unsigned short* orow = out + (size_t)row * DMv;
    *(ushort4*)(orow + t * 4)       = o0;
    *(ushort4*)(orow + 256 + t * 4) = o1;
}

// ---------------- fp32 -> bf16 weight conversion ------------------------------
__global__ __launch_bounds__(256) void w2bf_kernel(
    const float* __restrict__ in, unsigned short* __restrict__ out, int n)
{
    const int i = (blockIdx.x * 256 + threadIdx.x) * 4;
    if (i + 3 < n) {
        float4 v = *(const float4*)(in + i);
        ushort4 o;
        o.x = f2bf(v.x); o.y = f2bf(v.y); o.z = f2bf(v.z); o.w = f2bf(v.w);
        *(ushort4*)(out + i) = o;
    }
}

// ---------------- bf16 MFMA GEMM: C[M,N]fp32 = A[M,K]bf16 * W[N,K]bf16^T ------
__global__ __launch_bounds__(256) void bgemm_bt(
    const unsigned short* __restrict__ A, int lda,
    const unsigned short* __restrict__ W, int ldw,
    float* __restrict__ C, int ldc, int Kdim)
{
    __shared__ unsigned short Alds[128 * 32];
    __shared__ unsigned short Blds[128 * 32];
    const int t    = threadIdx.x;
    const int lane = t & 63;
    const int wv   = t >> 6;
    const int wm   = wv & 1;
    const int wn   = wv >> 1;
    const int m0 = blockIdx.y * 128, n0 = blockIdx.x * 128;

    const int srow = lane >> 2;
    const int sq   = (lane & 3) ^ ((srow >> 1) & 3);
    const unsigned short* Ag = A + (size_t)(m0 + wv * 16 + srow) * lda + sq * 8;
    const unsigned short* Wg = W + (size_t)(n0 + wv * 16 + srow) * ldw + sq * 8;

    f32x4 acc[4][4];
#pragma unroll
    for (int mi = 0; mi < 4; mi++)
#pragma unroll
        for (int ni = 0; ni < 4; ni++) acc[mi][ni] = (f32x4)0.0f;

    const int r = lane & 15;
    const int q = lane >> 4;

    for (int k0 = 0; k0 < Kdim; k0 += 32) {
        __syncthreads();
#pragma unroll
        for (int j = 0; j < 2; j++) {
            __builtin_amdgcn_global_load_lds(
                (const __attribute__((address_space(1))) unsigned int*)(Ag + (size_t)j * 64 * lda + k0),
                (__attribute__((address_space(3))) unsigned int*)(Alds + (wv * 16 + j * 64) * 32),
                16, 0, 0);
            __builtin_amdgcn_global_load_lds(
                (const __attribute__((address_space(1))) unsigned int*)(Wg + (size_t)j * 64 * ldw + k0),
                (__attribute__((address_space(3))) unsigned int*)(Blds + (wv * 16 + j * 64) * 32),
                16, 0, 0);
        }
        __syncthreads();

        short8 af[4], bf[4];
#pragma unroll
        for (int mi = 0; mi < 4; mi++) {
            const int rr = wm * 64 + mi * 16 + r;
            const int qq = q ^ ((r >> 1) & 3);
            af[mi] = *(const short8*)(Alds + rr * 32 + qq * 8);
        }
#pragma unroll
        for (int ni = 0; ni < 4; ni++) {
            const int rr = wn * 64 + ni * 16 + r;
            const int qq = q ^ ((r >> 1) & 3);
            bf[ni] = *(const short8*)(Blds + rr * 32 + qq * 8);
        }
#pragma unroll
        for (int mi = 0; mi < 4; mi++)
#pragma unroll
            for (int ni = 0; ni < 4; ni++)
                acc[mi][ni] = __builtin_amdgcn_mfma_f32_16x16x32_bf16(
                    af[mi], bf[ni], acc[mi][ni], 0, 0, 0);
    }

#pragma unroll
    for (int mi = 0; mi < 4; mi++)
#pragma unroll
        for (int ni = 0; ni < 4; ni++) {
            const int row = m0 + wm * 64 + mi * 16 + q * 4;
            const int col = n0 + wn * 64 + ni * 16 + r;
#pragma unroll
            for (int rg = 0; rg < 4; rg++)
                C[(size_t)(row + rg) * ldc + col] = acc[mi][ni][rg];
        }
}

// ---------------- x-proj split-K: Cp[ks] = A[:, ks*256:+256] * W[:, same]^T ---
// A: (MR x 1024), W: (64 x 1024), Cp: 4 slices of (MR x 64) partials.
// grid (MR/64, 4); 64x64 tile, BK=16, 4x4 microtile (same body as old sgemm).
__global__ __launch_bounds__(256) void xproj_sk(
    const float* __restrict__ A, const float* __restrict__ W,
    float* __restrict__ Cp, int MR)
{
    __shared__ float As[16][68];
    __shared__ float Ws[16][68];
    const int t  = threadIdx.x;
    const int m0 = blockIdx.x * 64;
    const int ks = blockIdx.y;
    const int rr = t >> 2;
    const int kq = (t & 3) << 2;
    const float* Ap = A + (size_t)(m0 + rr) * DIv + ks * 256 + kq;
    const float* Wp = W + (size_t)rr * DIv + ks * 256 + kq;
    const int tm = (t >> 4) << 2;
    const int tn = (t & 15) << 2;

    float acc[4][4];
#pragma unroll
    for (int i = 0; i < 4; i++)
#pragma unroll
        for (int j = 0; j < 4; j++) acc[i][j] = 0.0f;

    for (int k0 = 0; k0 < 256; k0 += 16) {
        __syncthreads();
        float4 av = *(const float4*)(Ap + k0);
        float4 wv = *(const float4*)(Wp + k0);
        As[kq + 0][rr] = av.x; As[kq + 1][rr] = av.y;
        As[kq + 2][rr] = av.z; As[kq + 3][rr] = av.w;
        Ws[kq + 0][rr] = wv.x; Ws[kq + 1][rr] = wv.y;
        Ws[kq + 2][rr] = wv.z; Ws[kq + 3][rr] = wv.w;
        __syncthreads();
#pragma unroll
        for (int k = 0; k < 16; k++) {
            float4 a4 = *(const float4*)&As[k][tm];
            float4 b4 = *(const float4*)&Ws[k][tn];
            float a[4] = {a4.x, a4.y, a4.z, a4.w};
            float bb[4] = {b4.x, b4.y, b4.z, b4.w};
#pragma unroll
            for (int i = 0; i < 4; i++)
#pragma unroll
                for (int j = 0; j < 4; j++) acc[i][j] += a[i] * bb[j];
        }
    }
    float* Co = Cp + (size_t)ks * MR * 64 + (size_t)(m0 + tm) * 64 + tn;
#pragma unroll
    for (int i = 0; i < 4; i++)
        *(float4*)(Co + (size_t)i * 64) = make_float4(acc[i][0], acc[i][1], acc[i][2], acc[i][3]);
}

// ---------------- x-proj reduce: dbl = sum of 4 K-slices ----------------------
__global__ __launch_bounds__(256) void xproj_red(
    const float* __restrict__ Cp, float* __restrict__ dbl, int MR)
{
    const size_t i = ((size_t)blockIdx.x * 256 + threadIdx.x) * 4;
    const size_t n = (size_t)MR * 64;
    float4 a = *(const float4*)(Cp + i);
    float4 b = *(const float4*)(Cp + n + i);
    float4 c = *(const float4*)(Cp + 2 * n + i);
    float4 d = *(const float4*)(Cp + 3 * n + i);
    float4 o;
    o.x = (a.x + b.x) + (c.x + d.x);
    o.y = (a.y + b.y) + (c.y + d.y);
    o.z = (a.z + b.z) + (c.z + d.z);
    o.w = (a.w + b.w) + (c.w + d.w);
    *(float4*)(dbl + i) = o;
}

// ---------------- depthwise causal conv(K=4) + bias + silu --------------------
__global__ __launch_bounds__(256) void conv_silu_kernel(
    const float* __restrict__ xz, const float* __restrict__ cw,
    const float* __restrict__ cb, float* __restrict__ xc)
{
    const int bl = blockIdx.x;
    const int l  = bl & (SEQL - 1);
    const int t  = threadIdx.x;
#pragma unroll
    for (int j = 0; j < 4; j++) {
        const int c = (j << 8) + t;
        float4 w4 = *(const float4*)(cw + c * 4);
        float wk[4] = {w4.x, w4.y, w4.z, w4.w};
        float acc = cb[c];
#pragma unroll
        for (int k = 0; k < KCv; k++) {
            const int lp = l - 3 + k;
            if (lp >= 0) {
                const long rowi = (long)bl + k - 3;
                acc += xz[(size_t)rowi * (2 * DIv) + c] * wk[k];
            }
        }
        const float sg = acc / (1.0f + __expf(-acc));
        xc[(size_t)bl * DIv + c] = sg;
    }
}

// ---------------- dt = softplus(dtr @ dt_w^T + dt_b) --------------------------
// 64 rows per block; dtr row address is wave-uniform -> scalar (s_load)
// broadcast; w row (32 floats) lives in 8 float4 VGPRs. grid (MR/64, DI/256).
__global__ __launch_bounds__(256) void dtk_kernel(
    const float* __restrict__ dbl, const float* __restrict__ dt_w,
    const float* __restrict__ dt_b, float* __restrict__ dt)
{
    const int t  = threadIdx.x;
    const int r0 = blockIdx.x * 64;
    const int di = blockIdx.y * 256 + t;

    const float4* wp = (const float4*)(dt_w + (size_t)di * DTRv);
    const float4 w0 = wp[0], w1 = wp[1], w2 = wp[2], w3 = wp[3];
    const float4 w4 = wp[4], w5 = wp[5], w6 = wp[6], w7 = wp[7];
    const float bias = dt_b[di];

    float* dto = dt + (size_t)r0 * DIv + di;
#pragma unroll 2
    for (int r = 0; r < 64; r++) {
        const float* dr = dbl + (size_t)(r0 + r) * 64;   // wave-uniform address
        float acc = bias;
        acc += dr[0]*w0.x + dr[1]*w0.y + dr[2]*w0.z + dr[3]*w0.w;
        acc += dr[4]*w1.x + dr[5]*w1.y + dr[6]*w1.z + dr[7]*w1.w;
        acc += dr[8]*w2.x + dr[9]*w2.y + dr[10]*w2.z + dr[11]*w2.w;
        acc += dr[12]*w3.x + dr[13]*w3.y + dr[14]*w3.z + dr[15]*w3.w;
        acc += dr[16]*w4.x + dr[17]*w4.y + dr[18]*w4.z + dr[19]*w4.w;
        acc += dr[20]*w5.x + dr[21]*w5.y + dr[22]*w5.z + dr[23]*w5.w;
        acc += dr[24]*w6.x + dr[25]*w6.y + dr[26]*w6.z + dr[27]*w6.w;
        acc += dr[28]*w7.x + dr[29]*w7.y + dr[30]*w7.z + dr[31]*w7.w;
        const float sp = (acc > 20.0f) ? acc : log1pf(__expf(acc));
        dto[(size_t)r * DIv] = sp;
    }
}

// ---------------- chunked scan, phase 1 ---------------------------------------
__global__ __launch_bounds__(256) void scan_p1(
    const float* __restrict__ dt, const float* __restrict__ xc,
    const float* __restrict__ dbl, const float* __restrict__ A_log,
    float* __restrict__ Pbuf, float* __restrict__ Sbuf)
{
    const int bid = blockIdx.x;
    const int dq  = bid & 3;
    const int g   = (bid >> 2) & (NG - 1);
    const int b   = bid >> 8;
    const int di  = (dq << 8) + threadIdx.x;

    __shared__ float sB[LCc][DSv];
    const float* blp = dbl + ((size_t)b * SEQL + (size_t)g * LCc) * 64;
    for (int e = threadIdx.x; e < LCc * DSv; e += 256) {
        const int l = e >> 4, s = e & 15;
        sB[l][s] = blp[l * 64 + 32 + s];
    }
    __syncthreads();

    float Areg[DSv], P[DSv], S[DSv];
#pragma unroll
    for (int s = 0; s < DSv; s++) {
        Areg[s] = -__expf(A_log[di * DSv + s]);
        P[s] = 1.0f;
        S[s] = 0.0f;
    }

    const float* dtp = dt + ((size_t)b * SEQL + (size_t)g * LCc) * DIv + di;
    const float* xp  = xc + ((size_t)b * SEQL + (size_t)g * LCc) * DIv + di;
#pragma unroll 2
    for (int l = 0; l < LCc; l++) {
        const float dtv = dtp[(size_t)l * DIv];
        const float xv  = xp[(size_t)l * DIv];
        const float u   = dtv * xv;
#pragma unroll
        for (int s = 0; s < DSv; s++) {
            const float a = __expf(dtv * Areg[s]);
            P[s] *= a;
            S[s] = S[s] * a + u * sB[l][s];
        }
    }

    float* pp = Pbuf + (((size_t)b * NG + g) * DSv) * DIv + di;
    float* sp = Sbuf + (((size_t)b * NG + g) * DSv) * DIv + di;
#pragma unroll
    for (int s = 0; s < DSv; s++) {
        pp[(size_t)s * DIv] = P[s];
        sp[(size_t)s * DIv] = S[s];
    }
}

// ---------------- chunked scan, phase 2 ---------------------------------------
__global__ __launch_bounds__(256) void scan_p2(
    const float* __restrict__ Pbuf, float* __restrict__ Sbuf)
{
    const int idx = blockIdx.x * 256 + threadIdx.x;
    const int di  = idx & (DIv - 1);
    const int s   = (idx >> 10) & 15;
    const int b   = idx >> 14;
    const size_t gstride = (size_t)DSv * DIv;
    size_t base = (((size_t)b * NG) * DSv + s) * DIv + di;
    float h = 0.0f;
    for (int g = 0; g < NG; g++) {
        const float P = Pbuf[base];
        const float S = Sbuf[base];
        Sbuf[base] = h;
        h = P * h + S;
        base += gstride;
    }
}

// ---------------- chunked scan, phase 3: seeded scan + gate -> bf16 y ---------
__global__ __launch_bounds__(256) void scan_p3(
    const float* __restrict__ dt, const float* __restrict__ xc,
    const float* __restrict__ dbl, const float* __restrict__ A_log,
    const float* __restrict__ Dp, const float* __restrict__ Sbuf,
    float* __restrict__ xzbuf)
{
    const int bid = blockIdx.x;
    const int dq  = bid & 3;
    const int g   = (bid >> 2) & (NG - 1);
    const int b   = bid >> 8;
    const int di  = (dq << 8) + threadIdx.x;

    __shared__ float sB[LCc][DSv];
    __shared__ float sC[LCc][DSv];
    const float* blp = dbl + ((size_t)b * SEQL + (size_t)g * LCc) * 64;
    for (int e = threadIdx.x; e < LCc * DSv; e += 256) {
        const int l = e >> 4, s = e & 15;
        sB[l][s] = blp[l * 64 + 32 + s];
        sC[l][s] = blp[l * 64 + 48 + s];
    }
    __syncthreads();

    float Areg[DSv], h[DSv];
    const float* seedp = Sbuf + (((size_t)b * NG + g) * DSv) * DIv + di;
#pragma unroll
    for (int s = 0; s < DSv; s++) {
        Areg[s] = -__expf(A_log[di * DSv + s]);
        h[s] = seedp[(size_t)s * DIv];
    }
    const float Dv = Dp[di];

    const float* dtp = dt + ((size_t)b * SEQL + (size_t)g * LCc) * DIv + di;
    const float* xp  = xc + ((size_t)b * SEQL + (size_t)g * LCc) * DIv + di;
    const size_t row0 = (size_t)b * SEQL + (size_t)g * LCc;
    const float* zp = xzbuf + row0 * (2 * DIv) + DIv + di;
    unsigned short* yb = (unsigned short*)xzbuf;   // bf16 rows, stride 4096

#pragma unroll 2
    for (int l = 0; l < LCc; l++) {
        const float dtv = dtp[(size_t)l * DIv];
        const float xv  = xp[(size_t)l * DIv];
        const float zv  = zp[(size_t)l * (2 * DIv)];
        const float u   = dtv * xv;
        float y = 0.0f;
#pragma unroll
        for (int s = 0; s < DSv; s++) {
            const float a = __expf(dtv * Areg[s]);
            h[s] = h[s] * a + u * sB[l][s];
            y += h[s] * sC[l][s];
        }
        y += xv * Dv;
        const float sg = zv / (1.0f + __expf(-zv));
        yb[(row0 + l) * (size_t)4096 + di] = f2bf(y * sg);
    }
}

extern "C" void kernel_launch(void* const* d_in, const int* in_sizes, int n_in,
                              void* d_out, int out_size, void* d_ws, size_t ws_size,
                              hipStream_t stream)
{
    const float* x       = (const float*)d_in[0];
    const float* ln_w    = (const float*)d_in[1];
    const float* ln_b    = (const float*)d_in[2];
    const float* in_w    = (const float*)d_in[3];
    const float* conv_w  = (const float*)d_in[4];
    const float* conv_b  = (const float*)d_in[5];
    const float* xproj_w = (const float*)d_in[6];
    const float* dt_w    = (const float*)d_in[7];
    const float* dt_b    = (const float*)d_in[8];
    const float* A_log   = (const float*)d_in[9];
    const float* Dvec    = (const float*)d_in[10];
    const float* out_w   = (const float*)d_in[11];
    float* out = (float*)d_out;

    const size_t wfix = (size_t)(2 * DIv * DMv + DMv * DIv) * 2;   // bytes
    const size_t perb = (size_t)SEQL * (DMv * 2 + 2 * DIv * 4 + DIv * 4 + 64 * 4 + DIv * 4)
                      + 2 * (size_t)NG * DSv * DIv * 4;
    const int CB = (ws_size >= wfix + 4 * perb) ? 4
                 : (ws_size >= wfix + 2 * perb) ? 2 : 1;

    char* wsb = (char*)d_ws;
    unsigned short* inwbf  = (unsigned short*)wsb;
    unsigned short* outwbf = inwbf + (size_t)2 * DIv * DMv;
    char* chunk0 = wsb + wfix;

    for (int i = 0; i < 2; i++) {
        const float* hin_base = (i == 0) ? x : out;
        w2bf_kernel<<<(2 * DIv * DMv) / 1024, 256, 0, stream>>>(
            in_w + (size_t)i * 2 * DIv * DMv, inwbf, 2 * DIv * DMv);
        w2bf_kernel<<<(DMv * DIv) / 1024, 256, 0, stream>>>(
            out_w + (size_t)i * DMv * DIv, outwbf, DMv * DIv);

        for (int c0 = 0; c0 < BATCH; c0 += CB) {
            const int MR = CB * SEQL;
            char* p = chunk0;
            unsigned short* hnbf = (unsigned short*)p; p += (size_t)MR * DMv * 2;
            float* xz   = (float*)p; p += (size_t)MR * 2 * DIv * 4;
            float* xc   = (float*)p; p += (size_t)MR * DIv * 4;
            float* dbl  = (float*)p; p += (size_t)MR * 64 * 4;
            float* dtb  = (float*)p; p += (size_t)MR * DIv * 4;
            float* Pbuf = (float*)p; p += (size_t)CB * NG * DSv * DIv * 4;
            float* Sbuf = (float*)p;
            const size_t row0 = (size_t)c0 * SEQL;

            ln_bf_kernel<<<MR, 64, 0, stream>>>(
                hin_base + row0 * DMv, ln_w + i * DMv, ln_b + i * DMv, hnbf);
            // in-proj: (MRx512)bf16 * (2048x512)bf16^T -> xz fp32 (MRx2048)
            bgemm_bt<<<dim3(2 * DIv / 128, MR / 128), 256, 0, stream>>>(
                hnbf, DMv, inwbf, DMv, xz, 2 * DIv, DMv);
            conv_silu_kernel<<<MR, 256, 0, stream>>>(
                xz, conv_w + i * DIv * KCv, conv_b + i * DIv, xc);
            // x-proj split-K into Pbuf (dead until scan_p1; MR*64*4 floats fits
            // exactly: CB*NG*DS*DI == MR*64*4 for LC=64), then reduce -> dbl.
            xproj_sk<<<dim3(MR / 64, 4), 256, 0, stream>>>(
                xc, xproj_w + (size_t)i * 64 * DIv, Pbuf, MR);
            xproj_red<<<(MR * 64) / 1024, 256, 0, stream>>>(Pbuf, dbl, MR);
            dtk_kernel<<<dim3(MR / 64, DIv / 256), 256, 0, stream>>>(
                dbl, dt_w + (size_t)i * DIv * DTRv, dt_b + i * DIv, dtb);
            scan_p1<<<CB * NG * 4, 256, 0, stream>>>(
                dtb, xc, dbl, A_log + (size_t)i * DIv * DSv, Pbuf, Sbuf);
            scan_p2<<<CB * 64, 256, 0, stream>>>(Pbuf, Sbuf);
            scan_p3<<<CB * NG * 4, 256, 0, stream>>>(
                dtb, xc, dbl, A_log + (size_t)i * DIv * DSv, Dvec + i * DIv, Sbuf, xz);
            // out-proj: y bf16 (in xz, lda=4096) * (512x1024)bf16^T -> out fp32
            bgemm_bt<<<dim3(DMv / 128, MR / 128), 256, 0, stream>>>(
                (const unsigned short*)xz, 2 * (2 * DIv), outwbf, DIv, out + row0 * DMv, DMv, DIv);
        }
    }
}

// Round 6
// 1135.605 us; speedup vs baseline: 5.3792x; 1.0678x over previous
//
#include <hip/hip_runtime.h>
#include <hip/hip_bf16.h>
#include <cstdint>

// mamba_model: DEPTH=2, B=4, L=4096, DM=512, DI=1024, DS=16, DTR=32, K=4
// Round 6: dt = softplus(dtr @ dt_w^T + b) -> MFMA GEMM with hi/lo bf16 split.
// R4/R5 dtk was allocator-hostage (VGPR_Count 28-32, weights never resident,
// 61-70us). New: A' = [dtr_hi|dtr_lo|dtr_hi] (MRx96 bf16), W' = [w_hi|w_hi|w_lo]
// (1024x96 bf16): A'.W' = dtr.w - lo.lo ~ fp32-accurate. K=96 = 3 BK iters of
// the proven bgemm structure; softplus+bias fused in the epilogue.
// dtrbf aliases the dead Sbuf region (scan_p1 overwrites it later) -> no perb
// growth; wcomb (192KB) added to wfix. Everything else unchanged from R5.

#define BATCH 4
#define SEQL  4096
#define DMv   512
#define DIv   1024
#define DSv   16
#define DTRv  32
#define KCv   4
#define LCc   64
#define NG    64

typedef __attribute__((ext_vector_type(8))) short short8;
typedef __attribute__((ext_vector_type(4))) float f32x4;

__device__ __forceinline__ unsigned short f2bf(float f) {
    unsigned int u = __builtin_bit_cast(unsigned int, f);
    u += 0x7FFFu + ((u >> 16) & 1u);          // round-to-nearest-even
    return (unsigned short)(u >> 16);
}
__device__ __forceinline__ float bf2f(unsigned short h) {
    unsigned int u = ((unsigned int)h) << 16;
    return __builtin_bit_cast(float, u);
}

// ---------------- LayerNorm -> bf16 out: one wave per row of 512 --------------
__global__ __launch_bounds__(64) void ln_bf_kernel(
    const float* __restrict__ in, const float* __restrict__ w,
    const float* __restrict__ b, unsigned short* __restrict__ out)
{
    const int row = blockIdx.x;
    const int t = threadIdx.x;
    const float* xr = in + (size_t)row * DMv;
    float4 v0 = *(const float4*)(xr + t * 4);
    float4 v1 = *(const float4*)(xr + 256 + t * 4);
    float s = v0.x + v0.y + v0.z + v0.w + v1.x + v1.y + v1.z + v1.w;
    float q = v0.x*v0.x + v0.y*v0.y + v0.z*v0.z + v0.w*v0.w
            + v1.x*v1.x + v1.y*v1.y + v1.z*v1.z + v1.w*v1.w;
    s += __shfl_xor(s, 1);  q += __shfl_xor(q, 1);
    s += __shfl_xor(s, 2);  q += __shfl_xor(q, 2);
    s += __shfl_xor(s, 4);  q += __shfl_xor(q, 4);
    s += __shfl_xor(s, 8);  q += __shfl_xor(q, 8);
    s += __shfl_xor(s, 16); q += __shfl_xor(q, 16);
    s += __shfl_xor(s, 32); q += __shfl_xor(q, 32);
    const float mean = s * (1.0f / DMv);
    const float var  = q * (1.0f / DMv) - mean * mean;
    const float rs   = rsqrtf(var + 1e-5f);

    float4 w0 = *(const float4*)(w + t * 4);
    float4 w1 = *(const float4*)(w + 256 + t * 4);
    float4 b0 = *(const float4*)(b + t * 4);
    float4 b1 = *(const float4*)(b + 256 + t * 4);
    ushort4 o0, o1;
    o0.x = f2bf((v0.x - mean) * rs * w0.x + b0.x);
    o0.y = f2bf((v0.y - mean) * rs * w0.y + b0.y);
    o0.z = f2bf((v0.z - mean) * rs * w0.z + b0.z);
    o0.w = f2bf((v0.w - mean) * rs * w0.w + b0.w);
    o1.x = f2bf((v1.x - mean) * rs * w1.x + b1.x);
    o1.y = f2bf((v1.y - mean) * rs * w1.y + b1.y);
    o1.z = f2bf((v1.z - mean) * rs * w1.z + b1.z);
    o1.w = f2bf((v1.w - mean) * rs * w1.w + b1.w);
    unsigned short* orow = out + (size_t)row * DMv;
    *(ushort4*)(orow + t * 4)       = o0;
    *(ushort4*)(orow + 256 + t * 4) = o1;
}

// ---------------- fp32 -> bf16 weight conversion ------------------------------
__global__ __launch_bounds__(256) void w2bf_kernel(
    const float* __restrict__ in, unsigned short* __restrict__ out, int n)
{
    const int i = (blockIdx.x * 256 + threadIdx.x) * 4;
    if (i + 3 < n) {
        float4 v = *(const float4*)(in + i);
        ushort4 o;
        o.x = f2bf(v.x); o.y = f2bf(v.y); o.z = f2bf(v.z); o.w = f2bf(v.w);
        *(ushort4*)(out + i) = o;
    }
}

// ---------------- wcomb: dt_w (1024x32 fp32) -> [w_hi|w_hi|w_lo] (1024x96) ----
__global__ __launch_bounds__(256) void wcomb_prep(
    const float* __restrict__ dt_w, unsigned short* __restrict__ wcomb)
{
    const int idx = blockIdx.x * 256 + threadIdx.x;   // 1024*8
    const int r  = idx >> 3;
    const int c4 = (idx & 7) * 4;
    float4 v = *(const float4*)(dt_w + (size_t)r * 32 + c4);
    ushort4 hi, lo;
    hi.x = f2bf(v.x); hi.y = f2bf(v.y); hi.z = f2bf(v.z); hi.w = f2bf(v.w);
    lo.x = f2bf(v.x - bf2f(hi.x)); lo.y = f2bf(v.y - bf2f(hi.y));
    lo.z = f2bf(v.z - bf2f(hi.z)); lo.w = f2bf(v.w - bf2f(hi.w));
    unsigned short* o = wcomb + (size_t)r * 96 + c4;
    *(ushort4*)(o)      = hi;
    *(ushort4*)(o + 32) = hi;
    *(ushort4*)(o + 64) = lo;
}

// ---------------- dtr_split: dbl cols 0..31 -> [hi|lo|hi] (MR x 96 bf16) ------
__global__ __launch_bounds__(256) void dtr_split(
    const float* __restrict__ dbl, unsigned short* __restrict__ dtrbf)
{
    const int idx = blockIdx.x * 256 + threadIdx.x;   // MR*8
    const int r  = idx >> 3;
    const int c4 = (idx & 7) * 4;
    float4 v = *(const float4*)(dbl + (size_t)r * 64 + c4);
    ushort4 hi, lo;
    hi.x = f2bf(v.x); hi.y = f2bf(v.y); hi.z = f2bf(v.z); hi.w = f2bf(v.w);
    lo.x = f2bf(v.x - bf2f(hi.x)); lo.y = f2bf(v.y - bf2f(hi.y));
    lo.z = f2bf(v.z - bf2f(hi.z)); lo.w = f2bf(v.w - bf2f(hi.w));
    unsigned short* o = dtrbf + (size_t)r * 96 + c4;
    *(ushort4*)(o)      = hi;
    *(ushort4*)(o + 32) = lo;
    *(ushort4*)(o + 64) = hi;
}

// ---------------- bf16 MFMA GEMM: C[M,N]fp32 = A[M,K]bf16 * W[N,K]bf16^T ------
__global__ __launch_bounds__(256) void bgemm_bt(
    const unsigned short* __restrict__ A, int lda,
    const unsigned short* __restrict__ W, int ldw,
    float* __restrict__ C, int ldc, int Kdim)
{
    __shared__ unsigned short Alds[128 * 32];
    __shared__ unsigned short Blds[128 * 32];
    const int t    = threadIdx.x;
    const int lane = t & 63;
    const int wv   = t >> 6;
    const int wm   = wv & 1;
    const int wn   = wv >> 1;
    const int m0 = blockIdx.y * 128, n0 = blockIdx.x * 128;

    const int srow = lane >> 2;
    const int sq   = (lane & 3) ^ ((srow >> 1) & 3);
    const unsigned short* Ag = A + (size_t)(m0 + wv * 16 + srow) * lda + sq * 8;
    const unsigned short* Wg = W + (size_t)(n0 + wv * 16 + srow) * ldw + sq * 8;

    f32x4 acc[4][4];
#pragma unroll
    for (int mi = 0; mi < 4; mi++)
#pragma unroll
        for (int ni = 0; ni < 4; ni++) acc[mi][ni] = (f32x4)0.0f;

    const int r = lane & 15;
    const int q = lane >> 4;

    for (int k0 = 0; k0 < Kdim; k0 += 32) {
        __syncthreads();
#pragma unroll
        for (int j = 0; j < 2; j++) {
            __builtin_amdgcn_global_load_lds(
                (const __attribute__((address_space(1))) unsigned int*)(Ag + (size_t)j * 64 * lda + k0),
                (__attribute__((address_space(3))) unsigned int*)(Alds + (wv * 16 + j * 64) * 32),
                16, 0, 0);
            __builtin_amdgcn_global_load_lds(
                (const __attribute__((address_space(1))) unsigned int*)(Wg + (size_t)j * 64 * ldw + k0),
                (__attribute__((address_space(3))) unsigned int*)(Blds + (wv * 16 + j * 64) * 32),
                16, 0, 0);
        }
        __syncthreads();

        short8 af[4], bf[4];
#pragma unroll
        for (int mi = 0; mi < 4; mi++) {
            const int rr = wm * 64 + mi * 16 + r;
            const int qq = q ^ ((r >> 1) & 3);
            af[mi] = *(const short8*)(Alds + rr * 32 + qq * 8);
        }
#pragma unroll
        for (int ni = 0; ni < 4; ni++) {
            const int rr = wn * 64 + ni * 16 + r;
            const int qq = q ^ ((r >> 1) & 3);
            bf[ni] = *(const short8*)(Blds + rr * 32 + qq * 8);
        }
#pragma unroll
        for (int mi = 0; mi < 4; mi++)
#pragma unroll
            for (int ni = 0; ni < 4; ni++)
                acc[mi][ni] = __builtin_amdgcn_mfma_f32_16x16x32_bf16(
                    af[mi], bf[ni], acc[mi][ni], 0, 0, 0);
    }

#pragma unroll
    for (int mi = 0; mi < 4; mi++)
#pragma unroll
        for (int ni = 0; ni < 4; ni++) {
            const int row = m0 + wm * 64 + mi * 16 + q * 4;
            const int col = n0 + wn * 64 + ni * 16 + r;
#pragma unroll
            for (int rg = 0; rg < 4; rg++)
                C[(size_t)(row + rg) * ldc + col] = acc[mi][ni][rg];
        }
}

// ---------------- dt MFMA GEMM (K=96) + fused bias+softplus -------------------
// A = dtrbf (MR x 96), W = wcomb (1024 x 96), dt = softplus(A.W^T + dt_b).
__global__ __launch_bounds__(256) void dt_mfma(
    const unsigned short* __restrict__ A,
    const unsigned short* __restrict__ W,
    const float* __restrict__ dt_b,
    float* __restrict__ dt)
{
    __shared__ unsigned short Alds[128 * 32];
    __shared__ unsigned short Blds[128 * 32];
    const int t    = threadIdx.x;
    const int lane = t & 63;
    const int wv   = t >> 6;
    const int wm   = wv & 1;
    const int wn   = wv >> 1;
    const int m0 = blockIdx.y * 128, n0 = blockIdx.x * 128;

    const int srow = lane >> 2;
    const int sq   = (lane & 3) ^ ((srow >> 1) & 3);
    const unsigned short* Ag = A + (size_t)(m0 + wv * 16 + srow) * 96 + sq * 8;
    const unsigned short* Wg = W + (size_t)(n0 + wv * 16 + srow) * 96 + sq * 8;

    f32x4 acc[4][4];
#pragma unroll
    for (int mi = 0; mi < 4; mi++)
#pragma unroll
        for (int ni = 0; ni < 4; ni++) acc[mi][ni] = (f32x4)0.0f;

    const int r = lane & 15;
    const int q = lane >> 4;

    for (int k0 = 0; k0 < 96; k0 += 32) {
        __syncthreads();
#pragma unroll
        for (int j = 0; j < 2; j++) {
            __builtin_amdgcn_global_load_lds(
                (const __attribute__((address_space(1))) unsigned int*)(Ag + (size_t)j * 64 * 96 + k0),
                (__attribute__((address_space(3))) unsigned int*)(Alds + (wv * 16 + j * 64) * 32),
                16, 0, 0);
            __builtin_amdgcn_global_load_lds(
                (const __attribute__((address_space(1))) unsigned int*)(Wg + (size_t)j * 64 * 96 + k0),
                (__attribute__((address_space(3))) unsigned int*)(Blds + (wv * 16 + j * 64) * 32),
                16, 0, 0);
        }
        __syncthreads();

        short8 af[4], bf[4];
#pragma unroll
        for (int mi = 0; mi < 4; mi++) {
            const int rr = wm * 64 + mi * 16 + r;
            const int qq = q ^ ((r >> 1) & 3);
            af[mi] = *(const short8*)(Alds + rr * 32 + qq * 8);
        }
#pragma unroll
        for (int ni = 0; ni < 4; ni++) {
            const int rr = wn * 64 + ni * 16 + r;
            const int qq = q ^ ((r >> 1) & 3);
            bf[ni] = *(const short8*)(Blds + rr * 32 + qq * 8);
        }
#pragma unroll
        for (int mi = 0; mi < 4; mi++)
#pragma unroll
            for (int ni = 0; ni < 4; ni++)
                acc[mi][ni] = __builtin_amdgcn_mfma_f32_16x16x32_bf16(
                    af[mi], bf[ni], acc[mi][ni], 0, 0, 0);
    }

#pragma unroll
    for (int ni = 0; ni < 4; ni++) {
        const int col = n0 + wn * 64 + ni * 16 + r;
        const float bias = dt_b[col];
#pragma unroll
        for (int mi = 0; mi < 4; mi++) {
            const int row = m0 + wm * 64 + mi * 16 + q * 4;
#pragma unroll
            for (int rg = 0; rg < 4; rg++) {
                const float v = acc[mi][ni][rg] + bias;
                const float sp = (v > 20.0f) ? v : log1pf(__expf(v));
                dt[(size_t)(row + rg) * DIv + col] = sp;
            }
        }
    }
}

// ---------------- x-proj split-K ----------------------------------------------
__global__ __launch_bounds__(256) void xproj_sk(
    const float* __restrict__ A, const float* __restrict__ W,
    float* __restrict__ Cp, int MR)
{
    __shared__ float As[16][68];
    __shared__ float Ws[16][68];
    const int t  = threadIdx.x;
    const int m0 = blockIdx.x * 64;
    const int ks = blockIdx.y;
    const int rr = t >> 2;
    const int kq = (t & 3) << 2;
    const float* Ap = A + (size_t)(m0 + rr) * DIv + ks * 256 + kq;
    const float* Wp = W + (size_t)rr * DIv + ks * 256 + kq;
    const int tm = (t >> 4) << 2;
    const int tn = (t & 15) << 2;

    float acc[4][4];
#pragma unroll
    for (int i = 0; i < 4; i++)
#pragma unroll
        for (int j = 0; j < 4; j++) acc[i][j] = 0.0f;

    for (int k0 = 0; k0 < 256; k0 += 16) {
        __syncthreads();
        float4 av = *(const float4*)(Ap + k0);
        float4 wv = *(const float4*)(Wp + k0);
        As[kq + 0][rr] = av.x; As[kq + 1][rr] = av.y;
        As[kq + 2][rr] = av.z; As[kq + 3][rr] = av.w;
        Ws[kq + 0][rr] = wv.x; Ws[kq + 1][rr] = wv.y;
        Ws[kq + 2][rr] = wv.z; Ws[kq + 3][rr] = wv.w;
        __syncthreads();
#pragma unroll
        for (int k = 0; k < 16; k++) {
            float4 a4 = *(const float4*)&As[k][tm];
            float4 b4 = *(const float4*)&Ws[k][tn];
            float a[4] = {a4.x, a4.y, a4.z, a4.w};
            float bb[4] = {b4.x, b4.y, b4.z, b4.w};
#pragma unroll
            for (int i = 0; i < 4; i++)
#pragma unroll
                for (int j = 0; j < 4; j++) acc[i][j] += a[i] * bb[j];
        }
    }
    float* Co = Cp + (size_t)ks * MR * 64 + (size_t)(m0 + tm) * 64 + tn;
#pragma unroll
    for (int i = 0; i < 4; i++)
        *(float4*)(Co + (size_t)i * 64) = make_float4(acc[i][0], acc[i][1], acc[i][2], acc[i][3]);
}

// ---------------- x-proj reduce -----------------------------------------------
__global__ __launch_bounds__(256) void xproj_red(
    const float* __restrict__ Cp, float* __restrict__ dbl, int MR)
{
    const size_t i = ((size_t)blockIdx.x * 256 + threadIdx.x) * 4;
    const size_t n = (size_t)MR * 64;
    float4 a = *(const float4*)(Cp + i);
    float4 b = *(const float4*)(Cp + n + i);
    float4 c = *(const float4*)(Cp + 2 * n + i);
    float4 d = *(const float4*)(Cp + 3 * n + i);
    float4 o;
    o.x = (a.x + b.x) + (c.x + d.x);
    o.y = (a.y + b.y) + (c.y + d.y);
    o.z = (a.z + b.z) + (c.z + d.z);
    o.w = (a.w + b.w) + (c.w + d.w);
    *(float4*)(dbl + i) = o;
}

// ---------------- depthwise causal conv(K=4) + bias + silu --------------------
__global__ __launch_bounds__(256) void conv_silu_kernel(
    const float* __restrict__ xz, const float* __restrict__ cw,
    const float* __restrict__ cb, float* __restrict__ xc)
{
    const int bl = blockIdx.x;
    const int l  = bl & (SEQL - 1);
    const int t  = threadIdx.x;
#pragma unroll
    for (int j = 0; j < 4; j++) {
        const int c = (j << 8) + t;
        float4 w4 = *(const float4*)(cw + c * 4);
        float wk[4] = {w4.x, w4.y, w4.z, w4.w};
        float acc = cb[c];
#pragma unroll
        for (int k = 0; k < KCv; k++) {
            const int lp = l - 3 + k;
            if (lp >= 0) {
                const long rowi = (long)bl + k - 3;
                acc += xz[(size_t)rowi * (2 * DIv) + c] * wk[k];
            }
        }
        const float sg = acc / (1.0f + __expf(-acc));
        xc[(size_t)bl * DIv + c] = sg;
    }
}

// ---------------- chunked scan, phase 1 ---------------------------------------
__global__ __launch_bounds__(256) void scan_p1(
    const float* __restrict__ dt, const float* __restrict__ xc,
    const float* __restrict__ dbl, const float* __restrict__ A_log,
    float* __restrict__ Pbuf, float* __restrict__ Sbuf)
{
    const int bid = blockIdx.x;
    const int dq  = bid & 3;
    const int g   = (bid >> 2) & (NG - 1);
    const int b   = bid >> 8;
    const int di  = (dq << 8) + threadIdx.x;

    __shared__ float sB[LCc][DSv];
    const float* blp = dbl + ((size_t)b * SEQL + (size_t)g * LCc) * 64;
    for (int e = threadIdx.x; e < LCc * DSv; e += 256) {
        const int l = e >> 4, s = e & 15;
        sB[l][s] = blp[l * 64 + 32 + s];
    }
    __syncthreads();

    float Areg[DSv], P[DSv], S[DSv];
#pragma unroll
    for (int s = 0; s < DSv; s++) {
        Areg[s] = -__expf(A_log[di * DSv + s]);
        P[s] = 1.0f;
        S[s] = 0.0f;
    }

    const float* dtp = dt + ((size_t)b * SEQL + (size_t)g * LCc) * DIv + di;
    const float* xp  = xc + ((size_t)b * SEQL + (size_t)g * LCc) * DIv + di;
#pragma unroll 2
    for (int l = 0; l < LCc; l++) {
        const float dtv = dtp[(size_t)l * DIv];
        const float xv  = xp[(size_t)l * DIv];
        const float u   = dtv * xv;
#pragma unroll
        for (int s = 0; s < DSv; s++) {
            const float a = __expf(dtv * Areg[s]);
            P[s] *= a;
            S[s] = S[s] * a + u * sB[l][s];
        }
    }

    float* pp = Pbuf + (((size_t)b * NG + g) * DSv) * DIv + di;
    float* sp = Sbuf + (((size_t)b * NG + g) * DSv) * DIv + di;
#pragma unroll
    for (int s = 0; s < DSv; s++) {
        pp[(size_t)s * DIv] = P[s];
        sp[(size_t)s * DIv] = S[s];
    }
}

// ---------------- chunked scan, phase 2 ---------------------------------------
__global__ __launch_bounds__(256) void scan_p2(
    const float* __restrict__ Pbuf, float* __restrict__ Sbuf)
{
    const int idx = blockIdx.x * 256 + threadIdx.x;
    const int di  = idx & (DIv - 1);
    const int s   = (idx >> 10) & 15;
    const int b   = idx >> 14;
    const size_t gstride = (size_t)DSv * DIv;
    size_t base = (((size_t)b * NG) * DSv + s) * DIv + di;
    float h = 0.0f;
    for (int g = 0; g < NG; g++) {
        const float P = Pbuf[base];
        const float S = Sbuf[base];
        Sbuf[base] = h;
        h = P * h + S;
        base += gstride;
    }
}

// ---------------- chunked scan, phase 3: seeded scan + gate -> bf16 y ---------
__global__ __launch_bounds__(256) void scan_p3(
    const float* __restrict__ dt, const float* __restrict__ xc,
    const float* __restrict__ dbl, const float* __restrict__ A_log,
    const float* __restrict__ Dp, const float* __restrict__ Sbuf,
    float* __restrict__ xzbuf)
{
    const int bid = blockIdx.x;
    const int dq  = bid & 3;
    const int g   = (bid >> 2) & (NG - 1);
    const int b   = bid >> 8;
    const int di  = (dq << 8) + threadIdx.x;

    __shared__ float sB[LCc][DSv];
    __shared__ float sC[LCc][DSv];
    const float* blp = dbl + ((size_t)b * SEQL + (size_t)g * LCc) * 64;
    for (int e = threadIdx.x; e < LCc * DSv; e += 256) {
        const int l = e >> 4, s = e & 15;
        sB[l][s] = blp[l * 64 + 32 + s];
        sC[l][s] = blp[l * 64 + 48 + s];
    }
    __syncthreads();

    float Areg[DSv], h[DSv];
    const float* seedp = Sbuf + (((size_t)b * NG + g) * DSv) * DIv + di;
#pragma unroll
    for (int s = 0; s < DSv; s++) {
        Areg[s] = -__expf(A_log[di * DSv + s]);
        h[s] = seedp[(size_t)s * DIv];
    }
    const float Dv = Dp[di];

    const float* dtp = dt + ((size_t)b * SEQL + (size_t)g * LCc) * DIv + di;
    const float* xp  = xc + ((size_t)b * SEQL + (size_t)g * LCc) * DIv + di;
    const size_t row0 = (size_t)b * SEQL + (size_t)g * LCc;
    const float* zp = xzbuf + row0 * (2 * DIv) + DIv + di;
    unsigned short* yb = (unsigned short*)xzbuf;   // bf16 rows, stride 4096

#pragma unroll 2
    for (int l = 0; l < LCc; l++) {
        const float dtv = dtp[(size_t)l * DIv];
        const float xv  = xp[(size_t)l * DIv];
        const float zv  = zp[(size_t)l * (2 * DIv)];
        const float u   = dtv * xv;
        float y = 0.0f;
#pragma unroll
        for (int s = 0; s < DSv; s++) {
            const float a = __expf(dtv * Areg[s]);
            h[s] = h[s] * a + u * sB[l][s];
            y += h[s] * sC[l][s];
        }
        y += xv * Dv;
        const float sg = zv / (1.0f + __expf(-zv));
        yb[(row0 + l) * (size_t)4096 + di] = f2bf(y * sg);
    }
}

extern "C" void kernel_launch(void* const* d_in, const int* in_sizes, int n_in,
                              void* d_out, int out_size, void* d_ws, size_t ws_size,
                              hipStream_t stream)
{
    const float* x       = (const float*)d_in[0];
    const float* ln_w    = (const float*)d_in[1];
    const float* ln_b    = (const float*)d_in[2];
    const float* in_w    = (const float*)d_in[3];
    const float* conv_w  = (const float*)d_in[4];
    const float* conv_b  = (const float*)d_in[5];
    const float* xproj_w = (const float*)d_in[6];
    const float* dt_w    = (const float*)d_in[7];
    const float* dt_b    = (const float*)d_in[8];
    const float* A_log   = (const float*)d_in[9];
    const float* Dvec    = (const float*)d_in[10];
    const float* out_w   = (const float*)d_in[11];
    float* out = (float*)d_out;

    // wfix: in_w bf16 + out_w bf16 + wcomb bf16(1024x96)
    const size_t wfix = ((size_t)(2 * DIv * DMv + DMv * DIv) + (size_t)DIv * 96) * 2;
    const size_t perb = (size_t)SEQL * (DMv * 2 + 2 * DIv * 4 + DIv * 4 + 64 * 4 + DIv * 4)
                      + 2 * (size_t)NG * DSv * DIv * 4;
    const int CB = (ws_size >= wfix + 4 * perb) ? 4
                 : (ws_size >= wfix + 2 * perb) ? 2 : 1;

    char* wsb = (char*)d_ws;
    unsigned short* inwbf  = (unsigned short*)wsb;
    unsigned short* outwbf = inwbf + (size_t)2 * DIv * DMv;
    unsigned short* wcomb  = outwbf + (size_t)DMv * DIv;
    char* chunk0 = wsb + wfix;

    for (int i = 0; i < 2; i++) {
        const float* hin_base = (i == 0) ? x : out;
        w2bf_kernel<<<(2 * DIv * DMv) / 1024, 256, 0, stream>>>(
            in_w + (size_t)i * 2 * DIv * DMv, inwbf, 2 * DIv * DMv);
        w2bf_kernel<<<(DMv * DIv) / 1024, 256, 0, stream>>>(
            out_w + (size_t)i * DMv * DIv, outwbf, DMv * DIv);
        wcomb_prep<<<(DIv * 8) / 256, 256, 0, stream>>>(
            dt_w + (size_t)i * DIv * DTRv, wcomb);

        for (int c0 = 0; c0 < BATCH; c0 += CB) {
            const int MR = CB * SEQL;
            char* p = chunk0;
            unsigned short* hnbf = (unsigned short*)p; p += (size_t)MR * DMv * 2;
            float* xz   = (float*)p; p += (size_t)MR * 2 * DIv * 4;
            float* xc   = (float*)p; p += (size_t)MR * DIv * 4;
            float* dbl  = (float*)p; p += (size_t)MR * 64 * 4;
            float* dtb  = (float*)p; p += (size_t)MR * DIv * 4;
            float* Pbuf = (float*)p; p += (size_t)CB * NG * DSv * DIv * 4;
            float* Sbuf = (float*)p;
            // dtrbf (MR x 96 bf16 = 1.5MB@CB=2) aliases Sbuf: written by
            // dtr_split, consumed by dt_mfma, then scan_p1 overwrites Sbuf.
            unsigned short* dtrbf = (unsigned short*)Sbuf;
            const size_t row0 = (size_t)c0 * SEQL;

            ln_bf_kernel<<<MR, 64, 0, stream>>>(
                hin_base + row0 * DMv, ln_w + i * DMv, ln_b + i * DMv, hnbf);
            bgemm_bt<<<dim3(2 * DIv / 128, MR / 128), 256, 0, stream>>>(
                hnbf, DMv, inwbf, DMv, xz, 2 * DIv, DMv);
            conv_silu_kernel<<<MR, 256, 0, stream>>>(
                xz, conv_w + i * DIv * KCv, conv_b + i * DIv, xc);
            xproj_sk<<<dim3(MR / 64, 4), 256, 0, stream>>>(
                xc, xproj_w + (size_t)i * 64 * DIv, Pbuf, MR);
            xproj_red<<<(MR * 64) / 1024, 256, 0, stream>>>(Pbuf, dbl, MR);
            dtr_split<<<(MR * 8) / 256, 256, 0, stream>>>(dbl, dtrbf);
            dt_mfma<<<dim3(DIv / 128, MR / 128), 256, 0, stream>>>(
                dtrbf, wcomb, dt_b + (size_t)i * DIv, dtb);
            scan_p1<<<CB * NG * 4, 256, 0, stream>>>(
                dtb, xc, dbl, A_log + (size_t)i * DIv * DSv, Pbuf, Sbuf);
            scan_p2<<<CB * 64, 256, 0, stream>>>(Pbuf, Sbuf);
            scan_p3<<<CB * NG * 4, 256, 0, stream>>>(
                dtb, xc, dbl, A_log + (size_t)i * DIv * DSv, Dvec + i * DIv, Sbuf, xz);
            bgemm_bt<<<dim3(DMv / 128, MR / 128), 256, 0, stream>>>(
                (const unsigned short*)xz, 2 * (2 * DIv), outwbf, DIv, out + row0 * DMv, DMv, DIv);
        }
    }
}